// Round 1
// baseline (1857.939 us; speedup 1.0000x reference)
//
#include <hip/hip_runtime.h>
#include <math.h>

// ---- problem constants ----
#define NFINE   80000
#define NCRS    2048
#define NSRC    1024
#define NNB     30
#define KP      15
#define C1D     128
#define C2D     256
#define GD      256
#define DGK     10
#define FINALD  32
#define DECIN   386   // 2 + 256 + 128
#define DECOUT  34

// =====================================================================
// Stage 1: x_f = kpconv(points_f, points_f, features(1ch), neighbors_f,
//                       kernel_points_f, W_kp1, extent=1.0)
// one block (128 threads) per point; out (NFINE, 128)
// =====================================================================
__global__ __launch_bounds__(128) void kpconv_fine(
    const float* __restrict__ pts, const float* __restrict__ feat,
    const int* __restrict__ nbr, const float* __restrict__ kp,
    const float* __restrict__ W, float* __restrict__ out)
{
    int n = blockIdx.x, t = threadIdx.x;
    __shared__ float kx[KP], ky[KP], kz[KP], kk[KP];
    __shared__ float contrib[NNB][KP];
    __shared__ float h[KP];
    if (t < KP) {
        float a = kp[t*3], b = kp[t*3+1], c = kp[t*3+2];
        kx[t] = a; ky[t] = b; kz[t] = c; kk[t] = a*a + b*b + c*c;
    }
    __syncthreads();
    if (t < NNB) {
        float qx = pts[n*3], qy = pts[n*3+1], qz = pts[n*3+2];
        int id = nbr[n*NNB + t];
        float rx = pts[id*3] - qx, ry = pts[id*3+1] - qy, rz = pts[id*3+2] - qz;
        float rr = rx*rx + ry*ry + rz*rz;
        float f = feat[id];
        for (int k = 0; k < KP; k++) {
            float d2 = rr + kk[k] - 2.f*(rx*kx[k] + ry*ky[k] + rz*kz[k]);
            float infl = fmaxf(1.f - sqrtf(fmaxf(d2, 1e-12f)), 0.f); // extent=1
            contrib[t][k] = infl * f;
        }
    }
    __syncthreads();
    if (t < KP) {
        float s = 0.f;
        for (int j = 0; j < NNB; j++) s += contrib[j][t];
        h[t] = s;
    }
    __syncthreads();
    float acc = 0.f;
    for (int k = 0; k < KP; k++) acc += h[k] * W[k*C1D + t];
    out[n*C1D + t] = acc;
}

// =====================================================================
// Stage 2: x_c = kpconv(points_c, points_f, x_f, pool_idx,
//                       kernel_points_c, W_kp2, extent=2.0)
// one block (256 threads) per coarse point; out (NCRS, 256)
// =====================================================================
__global__ __launch_bounds__(256) void kpconv_coarse(
    const float* __restrict__ pc, const float* __restrict__ pf,
    const float* __restrict__ xf, const int* __restrict__ pool,
    const float* __restrict__ kp, const float* __restrict__ W,
    float* __restrict__ out)
{
    int n = blockIdx.x, t = threadIdx.x;
    __shared__ float kx[KP], ky[KP], kz[KP], kk[KP];
    __shared__ float rel[NNB][4];
    __shared__ int   ids[NNB];
    __shared__ float infl[NNB][KP];
    __shared__ float nf[NNB][C1D];
    __shared__ float hh[KP][C1D];
    if (t < KP) {
        float a = kp[t*3], b = kp[t*3+1], c = kp[t*3+2];
        kx[t] = a; ky[t] = b; kz[t] = c; kk[t] = a*a + b*b + c*c;
    }
    if (t < NNB) {
        int id = pool[n*NNB + t]; ids[t] = id;
        float qx = pc[n*3], qy = pc[n*3+1], qz = pc[n*3+2];
        float rx = pf[id*3] - qx, ry = pf[id*3+1] - qy, rz = pf[id*3+2] - qz;
        rel[t][0] = rx; rel[t][1] = ry; rel[t][2] = rz;
        rel[t][3] = rx*rx + ry*ry + rz*rz;
    }
    __syncthreads();
    for (int i = t; i < NNB*KP; i += 256) {
        int j = i / KP, kq = i % KP;
        float d2 = rel[j][3] + kk[kq]
                 - 2.f*(rel[j][0]*kx[kq] + rel[j][1]*ky[kq] + rel[j][2]*kz[kq]);
        infl[j][kq] = fmaxf(1.f - sqrtf(fmaxf(d2, 1e-12f)) * 0.5f, 0.f); // extent=2
    }
    for (int i = t; i < NNB*C1D; i += 256) {
        int j = i >> 7, c = i & 127;
        nf[j][c] = xf[(size_t)ids[j]*C1D + c];
    }
    __syncthreads();
    for (int i = t; i < KP*C1D; i += 256) {
        int kq = i >> 7, c = i & 127;
        float s = 0.f;
        #pragma unroll
        for (int j = 0; j < NNB; j++) s += infl[j][kq] * nf[j][c];
        hh[kq][c] = s;
    }
    __syncthreads();
    float acc = 0.f;
    for (int kq = 0; kq < KP; kq++)
        for (int c = 0; c < C1D; c++)
            acc += hh[kq][c] * W[(size_t)(kq*C1D + c)*C2D + t];
    out[n*C2D + t] = acc;
}

// =====================================================================
// Generic linear: out[n,:] = in[n,:] @ W (+ b). block per row, COUT threads.
// =====================================================================
template<int CIN, int COUT, bool BIAS>
__global__ __launch_bounds__(COUT) void linear_kernel(
    const float* __restrict__ in, const float* __restrict__ W,
    const float* __restrict__ b, float* __restrict__ out)
{
    int n = blockIdx.x, t = threadIdx.x;
    __shared__ float xi[CIN];
    for (int i = t; i < CIN; i += COUT) xi[i] = in[n*CIN + i];
    __syncthreads();
    float acc = BIAS ? b[t] : 0.f;
    for (int c = 0; c < CIN; c++) acc += xi[c] * W[c*COUT + t];
    out[n*COUT + t] = acc;
}

// =====================================================================
// knn over the two coarse halves (d2 = sq[n]+sq[m]-2*dot, top-10 smallest,
// ties keep lower index -> matches jax.lax.top_k; set is all that matters)
// local indices 0..1023 within each half. 2048 threads total.
// =====================================================================
__global__ void knn_kernel(const float* __restrict__ pts, int* __restrict__ knn)
{
    int g = blockIdx.x * blockDim.x + threadIdx.x;
    if (g >= NCRS) return;
    int base = (g < NSRC) ? 0 : NSRC;
    int local = g - base;
    const float* P = pts + (size_t)base*3;
    float qx = P[local*3], qy = P[local*3+1], qz = P[local*3+2];
    float sqn = qx*qx + qy*qy + qz*qz;
    float bd[DGK]; int bi[DGK];
    #pragma unroll
    for (int i = 0; i < DGK; i++) { bd[i] = 3.4e38f; bi[i] = 0; }
    for (int m = 0; m < NSRC; m++) {
        float px = P[m*3], py = P[m*3+1], pz = P[m*3+2];
        float sqm = px*px + py*py + pz*pz;
        float d2 = sqn + sqm - 2.f*(qx*px + qy*py + qz*pz);
        if (d2 < bd[DGK-1]) {
            int pos = DGK - 1;
            while (pos > 0 && d2 < bd[pos-1]) {
                bd[pos] = bd[pos-1]; bi[pos] = bi[pos-1]; pos--;
            }
            bd[pos] = d2; bi[pos] = m;
        }
    }
    for (int i = 0; i < DGK; i++) knn[g*DGK + i] = bi[i];
}

// =====================================================================
// self_layer (DGCNN edge conv): out[n,d] = max_j relu(b[d] + x[n]·W1[:,d]
//                                   + (x[idx_j]-x[n])·W2[:,d])
// block per point, 256 threads (one per out channel). W read once per block.
// =====================================================================
__global__ __launch_bounds__(256) void self_layer_kernel(
    const float* __restrict__ x, const int* __restrict__ idx,
    const float* __restrict__ W, const float* __restrict__ b,
    float* __restrict__ out)
{
    int n = blockIdx.x, t = threadIdx.x;
    __shared__ float xc[GD];
    __shared__ float xd[DGK][GD];
    xc[t] = x[n*GD + t];
    __syncthreads();
    for (int i = t; i < DGK*GD; i += 256) {
        int j = i >> 8, c = i & 255;
        xd[j][c] = x[(size_t)idx[n*DGK + j]*GD + c] - xc[c];
    }
    __syncthreads();
    float base = b[t];
    for (int c = 0; c < GD; c++) base += xc[c] * W[c*GD + t];
    float s[DGK];
    #pragma unroll
    for (int j = 0; j < DGK; j++) s[j] = 0.f;
    for (int c = 0; c < GD; c++) {
        float w = W[(GD + c)*GD + t];
        #pragma unroll
        for (int j = 0; j < DGK; j++) s[j] += xd[j][c] * w;
    }
    float acc = 0.f;
    #pragma unroll
    for (int j = 0; j < DGK; j++) acc = fmaxf(acc, fmaxf(base + s[j], 0.f));
    out[n*GD + t] = acc;
}

// =====================================================================
// cross attention: msg for all 2048 rows; q row n attends over the OTHER half.
// 256 threads = 4 heads x 64 dims; one wave per head; online softmax.
// =====================================================================
__global__ __launch_bounds__(256) void attn_kernel(
    const float* __restrict__ q, const float* __restrict__ k,
    const float* __restrict__ v, float* __restrict__ msg)
{
    int n = blockIdx.x, t = threadIdx.x;
    int kbase = (n < NSRC) ? NSRC : 0;
    const float* kp = k + (size_t)kbase*GD;
    const float* vp = v + (size_t)kbase*GD;
    float qe = q[n*GD + t];
    float mr = -INFINITY, lr = 0.f, acc = 0.f;
    for (int m = 0; m < NSRC; m++) {
        float p = qe * kp[m*GD + t];
        #pragma unroll
        for (int off = 32; off >= 1; off >>= 1) p += __shfl_xor(p, off);
        p *= 0.125f; // 1/sqrt(64)
        float mn = fmaxf(mr, p);
        float scale = expf(mr - mn);
        float e = expf(p - mn);
        acc = acc*scale + e * vp[m*GD + t];
        lr  = lr*scale + e;
        mr = mn;
    }
    msg[n*GD + t] = acc / lr;
}

// out = x + [x, msg] @ Wm + bm
__global__ __launch_bounds__(256) void cross_combine(
    const float* __restrict__ x, const float* __restrict__ msg,
    const float* __restrict__ Wm, const float* __restrict__ bm,
    float* __restrict__ out)
{
    int n = blockIdx.x, t = threadIdx.x;
    __shared__ float xs[GD], ms[GD];
    xs[t] = x[n*GD + t]; ms[t] = msg[n*GD + t];
    __syncthreads();
    float acc = xs[t] + bm[t];
    for (int c = 0; c < GD; c++) acc += xs[c] * Wm[c*GD + t];
    for (int c = 0; c < GD; c++) acc += ms[c] * Wm[(GD + c)*GD + t];
    out[n*GD + t] = acc;
}

// =====================================================================
// proj + l2norm + score, fused. block per row.
// =====================================================================
__global__ __launch_bounds__(256) void proj_fused(
    const float* __restrict__ g3, const float* __restrict__ Wp,
    const float* __restrict__ bp, const float* __restrict__ Wsc,
    const float* __restrict__ bsc, float* __restrict__ feats,
    float* __restrict__ fnorm, float* __restrict__ scores)
{
    int n = blockIdx.x, t = threadIdx.x;
    __shared__ float xi[GD];
    __shared__ float red[256];
    xi[t] = g3[n*GD + t];
    __syncthreads();
    float acc = bp[t];
    for (int c = 0; c < GD; c++) acc += xi[c] * Wp[c*GD + t];
    feats[n*GD + t] = acc;
    red[t] = acc * acc; __syncthreads();
    for (int s = 128; s > 0; s >>= 1) { if (t < s) red[t] += red[t+s]; __syncthreads(); }
    float nrm = fmaxf(sqrtf(red[0]), 1e-12f);
    __syncthreads();
    fnorm[n*GD + t] = acc / nrm;
    red[t] = acc * Wsc[t]; __syncthreads();
    for (int s = 128; s > 0; s >>= 1) { if (t < s) red[t] += red[t+s]; __syncthreads(); }
    if (t == 0) scores[n] = red[0] + bsc[0];
}

// ip[n,m] = fnorm_src[n] . fnorm_tgt[m]
__global__ __launch_bounds__(256) void ip_kernel(
    const float* __restrict__ fnorm, float* __restrict__ ip)
{
    int n = blockIdx.x, t = threadIdx.x;
    __shared__ float xs[GD];
    xs[t] = fnorm[n*GD + t];
    __syncthreads();
    const float* ftgt = fnorm + (size_t)NSRC*GD;
    for (int m = t; m < NSRC; m += 256) {
        float s = 0.f;
        for (int c = 0; c < GD; c++) s += xs[c] * ftgt[m*GD + c];
        ip[n*NSRC + m] = s;
    }
}

// saliency: softmax(ip_row_or_col / T) . scores_other
template<bool COL>
__global__ __launch_bounds__(256) void saliency_kernel(
    const float* __restrict__ ip, const float* __restrict__ scores_other,
    const float* __restrict__ epsv, float* __restrict__ sal_out)
{
    int n = blockIdx.x, t = threadIdx.x;
    float T = expf(epsv[0]) + 0.03f;
    __shared__ float red[256];
    float vals[4];
    float m = -INFINITY;
    #pragma unroll
    for (int ii = 0; ii < 4; ii++) {
        int i = t + ii*256;
        float vv = COL ? ip[(size_t)i*NSRC + n] : ip[(size_t)n*NSRC + i];
        vv /= T;
        vals[ii] = vv;
        m = fmaxf(m, vv);
    }
    red[t] = m; __syncthreads();
    for (int s = 128; s > 0; s >>= 1) { if (t < s) red[t] = fmaxf(red[t], red[t+s]); __syncthreads(); }
    float mx = red[0]; __syncthreads();
    float se = 0.f, ws = 0.f;
    #pragma unroll
    for (int ii = 0; ii < 4; ii++) {
        int i = t + ii*256;
        float e = expf(vals[ii] - mx);
        se += e; ws += e * scores_other[i];
    }
    red[t] = se; __syncthreads();
    for (int s = 128; s > 0; s >>= 1) { if (t < s) red[t] += red[t+s]; __syncthreads(); }
    float S = red[0]; __syncthreads();
    red[t] = ws; __syncthreads();
    for (int s = 128; s > 0; s >>= 1) { if (t < s) red[t] += red[t+s]; __syncthreads(); }
    if (t == 0) sal_out[n] = red[0] / S;
}

// =====================================================================
// decoder: per fine point, 386-dim concat @ W_dec (386x34) + b_dec,
// l2norm first 32, sigmoid last 2. one wave per row, 4 rows per block.
// =====================================================================
__global__ __launch_bounds__(256) void decoder_kernel(
    const float* __restrict__ feats, const float* __restrict__ scores,
    const float* __restrict__ sal, const float* __restrict__ skip,
    const int* __restrict__ ups, const float* __restrict__ Wd,
    const float* __restrict__ bd, float* __restrict__ outf,
    float* __restrict__ outso, float* __restrict__ outss)
{
    int t = threadIdx.x;
    int w = t >> 6, lane = t & 63;
    int row = blockIdx.x * 4 + w;   // 20000*4 == 80000 exactly
    __shared__ float xin[4][DECIN + 2];
    int u = ups[row];
    for (int c = lane; c < DECIN; c += 64) {
        float vv;
        if (c == 0)        vv = scores[u];
        else if (c == 1)   vv = sal[u];
        else if (c < 258)  vv = feats[(size_t)u*GD + (c - 2)];
        else               vv = skip[(size_t)row*C1D + (c - 258)];
        xin[w][c] = vv;
    }
    __syncthreads();
    float acc = 0.f;
    if (lane < DECOUT) {
        acc = bd[lane];
        for (int c = 0; c < DECIN; c++) acc += xin[w][c] * Wd[c*DECOUT + lane];
    }
    float sq = (lane < FINALD) ? acc*acc : 0.f;
    #pragma unroll
    for (int off = 32; off >= 1; off >>= 1) sq += __shfl_xor(sq, off);
    if (lane < FINALD) {
        float nrm = fmaxf(sqrtf(sq), 1e-12f);
        outf[(size_t)row*FINALD + lane] = acc / nrm;
    } else if (lane < DECOUT) {
        float s = 1.f / (1.f + expf(-acc));
        s = fminf(fmaxf(s, 0.f), 1.f);
        if (!(s == s)) s = 0.f;           // NaN guard
        if (lane == FINALD) outso[row] = s;
        else                outss[row] = s;
    }
}

// =====================================================================
extern "C" void kernel_launch(void* const* d_in, const int* in_sizes, int n_in,
                              void* d_out, int out_size, void* d_ws, size_t ws_size,
                              hipStream_t stream)
{
    const float* points_f     = (const float*)d_in[0];
    const float* points_c     = (const float*)d_in[1];
    const float* features     = (const float*)d_in[2];
    const float* kp_f         = (const float*)d_in[3];
    const float* kp_c         = (const float*)d_in[4];
    const float* W_kp1        = (const float*)d_in[5];
    const float* W_kp2        = (const float*)d_in[6];
    const float* W_bottle     = (const float*)d_in[7];
    const float* b_bottle     = (const float*)d_in[8];
    const float* W_self1      = (const float*)d_in[9];
    const float* b_self1      = (const float*)d_in[10];
    const float* Wq           = (const float*)d_in[11];
    const float* Wk           = (const float*)d_in[12];
    const float* Wv           = (const float*)d_in[13];
    const float* W_cross      = (const float*)d_in[14];
    const float* b_cross      = (const float*)d_in[15];
    const float* W_self2      = (const float*)d_in[16];
    const float* b_self2      = (const float*)d_in[17];
    const float* W_proj       = (const float*)d_in[18];
    const float* b_proj       = (const float*)d_in[19];
    const float* W_score      = (const float*)d_in[20];
    const float* b_score      = (const float*)d_in[21];
    const float* epsilon      = (const float*)d_in[22];
    const float* W_dec        = (const float*)d_in[23];
    const float* b_dec        = (const float*)d_in[24];
    const int*   neighbors_f  = (const int*)d_in[25];
    const int*   pool_idx     = (const int*)d_in[26];
    const int*   upsample_idx = (const int*)d_in[27];

    float* ws = (float*)d_ws;
    size_t o = 0;
    auto alloc = [&](size_t nfl) { float* p = ws + o; o += (nfl + 63) & ~(size_t)63; return p; };
    float* x_f     = alloc((size_t)NFINE * C1D);
    float* x_c     = alloc((size_t)NCRS * C2D);
    float* feats_c = alloc((size_t)NCRS * GD);
    float* g1      = alloc((size_t)NCRS * GD);
    float* qb      = alloc((size_t)NCRS * GD);
    float* kb      = alloc((size_t)NCRS * GD);
    float* vb      = alloc((size_t)NCRS * GD);
    float* msg     = alloc((size_t)NCRS * GD);
    float* g2      = alloc((size_t)NCRS * GD);
    float* g3      = alloc((size_t)NCRS * GD);
    float* feats   = alloc((size_t)NCRS * GD);
    float* fnorm   = alloc((size_t)NCRS * GD);
    float* ip      = alloc((size_t)NSRC * NSRC);
    float* scores  = alloc(NCRS);
    float* sal     = alloc(NCRS);
    int*   knn     = (int*)alloc(NCRS * DGK);

    float* outf  = (float*)d_out;
    float* outso = outf + (size_t)NFINE * FINALD;
    float* outss = outso + NFINE;

    // encoder
    kpconv_fine<<<NFINE, 128, 0, stream>>>(points_f, features, neighbors_f, kp_f, W_kp1, x_f);
    kpconv_coarse<<<NCRS, 256, 0, stream>>>(points_c, points_f, x_f, pool_idx, kp_c, W_kp2, x_c);
    linear_kernel<C2D, GD, true><<<NCRS, GD, 0, stream>>>(x_c, W_bottle, b_bottle, feats_c);

    // GNN
    knn_kernel<<<8, 256, 0, stream>>>(points_c, knn);
    self_layer_kernel<<<NSRC, 256, 0, stream>>>(feats_c, knn, W_self1, b_self1, g1);
    self_layer_kernel<<<NSRC, 256, 0, stream>>>(feats_c + (size_t)NSRC*GD, knn + NSRC*DGK,
                                                W_self1, b_self1, g1 + (size_t)NSRC*GD);
    linear_kernel<GD, GD, false><<<NCRS, GD, 0, stream>>>(g1, Wq, nullptr, qb);
    linear_kernel<GD, GD, false><<<NCRS, GD, 0, stream>>>(g1, Wk, nullptr, kb);
    linear_kernel<GD, GD, false><<<NCRS, GD, 0, stream>>>(g1, Wv, nullptr, vb);
    attn_kernel<<<NCRS, 256, 0, stream>>>(qb, kb, vb, msg);
    cross_combine<<<NCRS, 256, 0, stream>>>(g1, msg, W_cross, b_cross, g2);
    self_layer_kernel<<<NSRC, 256, 0, stream>>>(g2, knn, W_self2, b_self2, g3);
    self_layer_kernel<<<NSRC, 256, 0, stream>>>(g2 + (size_t)NSRC*GD, knn + NSRC*DGK,
                                                W_self2, b_self2, g3 + (size_t)NSRC*GD);

    // head
    proj_fused<<<NCRS, 256, 0, stream>>>(g3, W_proj, b_proj, W_score, b_score, feats, fnorm, scores);
    ip_kernel<<<NSRC, 256, 0, stream>>>(fnorm, ip);
    saliency_kernel<false><<<NSRC, 256, 0, stream>>>(ip, scores + NSRC, epsilon, sal);
    saliency_kernel<true><<<NSRC, 256, 0, stream>>>(ip, scores, epsilon, sal + NSRC);

    // decoder
    decoder_kernel<<<NFINE/4, 256, 0, stream>>>(feats, scores, sal, x_f, upsample_idx,
                                                W_dec, b_dec, outf, outso, outss);
}

// Round 2
// 1103.775 us; speedup vs baseline: 1.6833x; 1.6833x over previous
//
#include <hip/hip_runtime.h>
#include <math.h>

// ---- problem constants ----
#define NFINE   80000
#define NCRS    2048
#define NSRC    1024
#define NNB     30
#define KP      15
#define C1D     128
#define C2D     256
#define GD      256
#define DGK     10
#define FINALD  32
#define DECIN   386
#define DECOUT  34

#define NCHUNK  8      // attention key-split
#define CHUNK   128    // 1024 / NCHUNK
#define CTILE   4      // coarse points per block in kpconv_coarse
#define LROWS   8      // row tile for linear-ish kernels

// =====================================================================
// Stage 1: kpconv fine — one wave per point, 4 points per block.
// =====================================================================
__global__ __launch_bounds__(256) void kpconv_fine(
    const float* __restrict__ pts, const float* __restrict__ feat,
    const int* __restrict__ nbr, const float* __restrict__ kp,
    const float* __restrict__ W, float* __restrict__ out)
{
    int t = threadIdx.x, w = t >> 6, lane = t & 63;
    int n = blockIdx.x * 4 + w;
    __shared__ float contrib[4][NNB][KP + 1];
    __shared__ float h[4][KP + 1];
    float kx[KP], ky[KP], kz[KP], kk[KP];
#pragma unroll
    for (int k = 0; k < KP; k++) {
        kx[k] = kp[k*3]; ky[k] = kp[k*3+1]; kz[k] = kp[k*3+2];
        kk[k] = kx[k]*kx[k] + ky[k]*ky[k] + kz[k]*kz[k];
    }
    if (lane < NNB) {
        float qx = pts[n*3], qy = pts[n*3+1], qz = pts[n*3+2];
        int id = nbr[n*NNB + lane];
        float rx = pts[id*3]-qx, ry = pts[id*3+1]-qy, rz = pts[id*3+2]-qz;
        float rr = rx*rx + ry*ry + rz*rz;
        float f = feat[id];
#pragma unroll
        for (int k = 0; k < KP; k++) {
            float d2 = rr + kk[k] - 2.f*(rx*kx[k] + ry*ky[k] + rz*kz[k]);
            float infl = fmaxf(1.f - sqrtf(fmaxf(d2, 1e-12f)), 0.f); // extent=1
            contrib[w][lane][k] = infl * f;
        }
    }
    __syncthreads();
    if (lane < KP) {
        float s = 0.f;
#pragma unroll
        for (int j = 0; j < NNB; j++) s += contrib[w][j][lane];
        h[w][lane] = s;
    }
    __syncthreads();
    float a0 = 0.f, a1 = 0.f;
#pragma unroll
    for (int k = 0; k < KP; k++) {
        float hk = h[w][k];
        a0 += hk * W[k*C1D + lane];
        a1 += hk * W[k*C1D + 64 + lane];
    }
    out[(size_t)n*C1D + lane]      = a0;
    out[(size_t)n*C1D + 64 + lane] = a1;
}

// =====================================================================
// Stage 2: kpconv coarse — CTILE=4 points per block; hh laid out
// [1920][4] so the W pass reads one broadcast float4 per W element.
// =====================================================================
__global__ __launch_bounds__(256) void kpconv_coarse(
    const float* __restrict__ pc, const float* __restrict__ pf,
    const float* __restrict__ xf, const int* __restrict__ pool,
    const float* __restrict__ kp, const float* __restrict__ W,
    float* __restrict__ out)
{
    int t = threadIdx.x;
    int n0 = blockIdx.x * CTILE;
    __shared__ float kx[KP], ky[KP], kz[KP], kk[KP];
    __shared__ float rel[NNB][4];
    __shared__ int   ids[NNB];
    __shared__ float infl[NNB][KP];
    __shared__ float nf[NNB][C1D];
    __shared__ float hh[KP*C1D][CTILE];   // 30720 B
    if (t < KP) {
        float a = kp[t*3], b = kp[t*3+1], c = kp[t*3+2];
        kx[t] = a; ky[t] = b; kz[t] = c; kk[t] = a*a + b*b + c*c;
    }
    for (int p = 0; p < CTILE; p++) {
        int n = n0 + p;
        __syncthreads();   // previous iteration readers done / kpt visible
        if (t < NNB) {
            int id = pool[n*NNB + t]; ids[t] = id;
            float qx = pc[n*3], qy = pc[n*3+1], qz = pc[n*3+2];
            float rx = pf[id*3]-qx, ry = pf[id*3+1]-qy, rz = pf[id*3+2]-qz;
            rel[t][0] = rx; rel[t][1] = ry; rel[t][2] = rz;
            rel[t][3] = rx*rx + ry*ry + rz*rz;
        }
        __syncthreads();
        for (int i = t; i < NNB*KP; i += 256) {
            int j = i / KP, kq = i % KP;
            float d2 = rel[j][3] + kk[kq]
                     - 2.f*(rel[j][0]*kx[kq] + rel[j][1]*ky[kq] + rel[j][2]*kz[kq]);
            infl[j][kq] = fmaxf(1.f - sqrtf(fmaxf(d2, 1e-12f)) * 0.5f, 0.f); // extent=2
        }
        for (int i = t; i < NNB*C1D; i += 256) {
            int j = i >> 7, c = i & 127;
            nf[j][c] = xf[(size_t)ids[j]*C1D + c];
        }
        __syncthreads();
        for (int i = t; i < KP*C1D; i += 256) {
            int kq = i >> 7, c = i & 127;
            float s = 0.f;
#pragma unroll
            for (int j = 0; j < NNB; j++) s += infl[j][kq] * nf[j][c];
            hh[i][p] = s;
        }
    }
    __syncthreads();
    float a0 = 0.f, a1 = 0.f, a2 = 0.f, a3 = 0.f;
    for (int i = 0; i < KP*C1D; i++) {
        float w = W[(size_t)i*C2D + t];
        float4 h4 = *(const float4*)&hh[i][0];   // broadcast
        a0 += h4.x*w; a1 += h4.y*w; a2 += h4.z*w; a3 += h4.w*w;
    }
    out[(size_t)(n0+0)*C2D + t] = a0;
    out[(size_t)(n0+1)*C2D + t] = a1;
    out[(size_t)(n0+2)*C2D + t] = a2;
    out[(size_t)(n0+3)*C2D + t] = a3;
}

// =====================================================================
// Row-tiled linear: LROWS rows per block, W read once per block.
// =====================================================================
template<int CIN, int COUT, bool BIAS>
__global__ __launch_bounds__(COUT) void linear_rows(
    const float* __restrict__ in, const float* __restrict__ W,
    const float* __restrict__ b, float* __restrict__ out)
{
    int t = threadIdx.x, n0 = blockIdx.x * LROWS;
    __shared__ float xi[CIN][LROWS];
    for (int i = t; i < LROWS*CIN; i += COUT) {
        int r = i / CIN, c = i % CIN;
        xi[c][r] = in[(size_t)(n0+r)*CIN + c];
    }
    __syncthreads();
    float a[LROWS];
#pragma unroll
    for (int r = 0; r < LROWS; r++) a[r] = BIAS ? b[t] : 0.f;
    for (int c = 0; c < CIN; c++) {
        float wv = W[c*COUT + t];
        float4 x0 = *(const float4*)&xi[c][0];
        float4 x1 = *(const float4*)&xi[c][4];
        a[0] += x0.x*wv; a[1] += x0.y*wv; a[2] += x0.z*wv; a[3] += x0.w*wv;
        a[4] += x1.x*wv; a[5] += x1.y*wv; a[6] += x1.z*wv; a[7] += x1.w*wv;
    }
#pragma unroll
    for (int r = 0; r < LROWS; r++) out[(size_t)(n0+r)*COUT + t] = a[r];
}

// fused q,k,v projections (shares staged input rows)
__global__ __launch_bounds__(256) void qkv_kernel(
    const float* __restrict__ x, const float* __restrict__ Wq,
    const float* __restrict__ Wk, const float* __restrict__ Wv,
    float* __restrict__ qb, float* __restrict__ kb, float* __restrict__ vb)
{
    int t = threadIdx.x, n0 = blockIdx.x * LROWS;
    __shared__ float xi[GD][LROWS];
    for (int i = t; i < LROWS*GD; i += 256) {
        int r = i >> 8, c = i & 255;
        xi[c][r] = x[(size_t)(n0+r)*GD + c];
    }
    __syncthreads();
    const float* Ws[3] = {Wq, Wk, Wv};
    float* outs[3] = {qb, kb, vb};
#pragma unroll
    for (int m = 0; m < 3; m++) {
        const float* W = Ws[m];
        float a[LROWS];
#pragma unroll
        for (int r = 0; r < LROWS; r++) a[r] = 0.f;
        for (int c = 0; c < GD; c++) {
            float wv = W[c*GD + t];
            float4 x0 = *(const float4*)&xi[c][0];
            float4 x1 = *(const float4*)&xi[c][4];
            a[0] += x0.x*wv; a[1] += x0.y*wv; a[2] += x0.z*wv; a[3] += x0.w*wv;
            a[4] += x1.x*wv; a[5] += x1.y*wv; a[6] += x1.z*wv; a[7] += x1.w*wv;
        }
        float* o = outs[m];
#pragma unroll
        for (int r = 0; r < LROWS; r++) o[(size_t)(n0+r)*GD + t] = a[r];
    }
}

// =====================================================================
// knn (unchanged)
// =====================================================================
__global__ void knn_kernel(const float* __restrict__ pts, int* __restrict__ knn)
{
    int g = blockIdx.x * blockDim.x + threadIdx.x;
    if (g >= NCRS) return;
    int base = (g < NSRC) ? 0 : NSRC;
    int local = g - base;
    const float* P = pts + (size_t)base*3;
    float qx = P[local*3], qy = P[local*3+1], qz = P[local*3+2];
    float sqn = qx*qx + qy*qy + qz*qz;
    float bd[DGK]; int bi[DGK];
#pragma unroll
    for (int i = 0; i < DGK; i++) { bd[i] = 3.4e38f; bi[i] = 0; }
    for (int m = 0; m < NSRC; m++) {
        float px = P[m*3], py = P[m*3+1], pz = P[m*3+2];
        float sqm = px*px + py*py + pz*pz;
        float d2 = sqn + sqm - 2.f*(qx*px + qy*py + qz*pz);
        if (d2 < bd[DGK-1]) {
            int pos = DGK - 1;
            while (pos > 0 && d2 < bd[pos-1]) {
                bd[pos] = bd[pos-1]; bi[pos] = bi[pos-1]; pos--;
            }
            bd[pos] = d2; bi[pos] = m;
        }
    }
    for (int i = 0; i < DGK; i++) knn[g*DGK + i] = bi[i];
}

// =====================================================================
// self_layer — xd transposed [c][j] (padded 12) for float4 LDS reads.
// =====================================================================
__global__ __launch_bounds__(256) void self_layer_kernel(
    const float* __restrict__ x, const int* __restrict__ idx,
    const float* __restrict__ W, const float* __restrict__ b,
    float* __restrict__ out)
{
    int n = blockIdx.x, t = threadIdx.x;
    __shared__ float xc[GD];
    __shared__ float xd[GD][12];
    xc[t] = x[(size_t)n*GD + t];
    __syncthreads();
    for (int i = t; i < DGK*GD; i += 256) {
        int j = i >> 8, c = i & 255;
        xd[c][j] = x[(size_t)idx[n*DGK + j]*GD + c] - xc[c];
    }
    __syncthreads();
    float base = b[t];
    float s[12];
#pragma unroll
    for (int j = 0; j < 12; j++) s[j] = 0.f;
    for (int c = 0; c < GD; c++) {
        float w1 = W[c*GD + t];
        float w2 = W[(GD + c)*GD + t];
        base += xc[c] * w1;
        float4 xa = *(const float4*)&xd[c][0];
        float4 xb = *(const float4*)&xd[c][4];
        float4 xq = *(const float4*)&xd[c][8];   // lanes 10,11 are pad garbage (unused)
        s[0] += xa.x*w2; s[1] += xa.y*w2; s[2] += xa.z*w2; s[3]  += xa.w*w2;
        s[4] += xb.x*w2; s[5] += xb.y*w2; s[6] += xb.z*w2; s[7]  += xb.w*w2;
        s[8] += xq.x*w2; s[9] += xq.y*w2; s[10]+= xq.z*w2; s[11] += xq.w*w2;
    }
    float acc = 0.f;
#pragma unroll
    for (int j = 0; j < DGK; j++) acc = fmaxf(acc, fmaxf(base + s[j], 0.f));
    out[(size_t)n*GD + t] = acc;
}

// =====================================================================
// attention: split-K flash. thread = (row, head, chunk). q/acc in regs,
// K/V rows wave-broadcast. Then merge partials.
// =====================================================================
__global__ __launch_bounds__(256, 1) void attn_partial(
    const float* __restrict__ qb, const float* __restrict__ kb,
    const float* __restrict__ vb, float* __restrict__ pm,
    float* __restrict__ pl, float* __restrict__ pacc)
{
    int g = blockIdx.x * 256 + threadIdx.x;
    int row = g & (NCRS - 1);
    int h = (g >> 11) & 3;
    int chunk = g >> 13;
    int kbase = (row < NSRC) ? NSRC : 0;

    const float4* q4 = (const float4*)(qb + (size_t)row*GD + h*64);
    float4 q[16];
#pragma unroll
    for (int i = 0; i < 16; i++) q[i] = q4[i];
    float4 a[16];
#pragma unroll
    for (int i = 0; i < 16; i++) a[i] = make_float4(0.f, 0.f, 0.f, 0.f);
    float mr = -INFINITY, lr = 0.f;

    const float* kbp = kb + ((size_t)(kbase + chunk*CHUNK))*GD + h*64;
    const float* vbp = vb + ((size_t)(kbase + chunk*CHUNK))*GD + h*64;
    for (int j = 0; j < CHUNK; j++) {
        const float4* kr = (const float4*)(kbp + (size_t)j*GD);
        float d0 = 0.f, d1 = 0.f, d2 = 0.f, d3 = 0.f;
#pragma unroll
        for (int i = 0; i < 16; i += 4) {
            float4 k0 = kr[i], k1 = kr[i+1], k2 = kr[i+2], k3 = kr[i+3];
            d0 += q[i].x*k0.x + q[i].y*k0.y + q[i].z*k0.z + q[i].w*k0.w;
            d1 += q[i+1].x*k1.x + q[i+1].y*k1.y + q[i+1].z*k1.z + q[i+1].w*k1.w;
            d2 += q[i+2].x*k2.x + q[i+2].y*k2.y + q[i+2].z*k2.z + q[i+2].w*k2.w;
            d3 += q[i+3].x*k3.x + q[i+3].y*k3.y + q[i+3].z*k3.z + q[i+3].w*k3.w;
        }
        float p = ((d0 + d1) + (d2 + d3)) * 0.125f;   // 1/sqrt(64)
        float mn = fmaxf(mr, p);
        float sc = __expf(mr - mn);
        float e  = __expf(p - mn);
        lr = lr*sc + e;
        const float4* vr = (const float4*)(vbp + (size_t)j*GD);
#pragma unroll
        for (int i = 0; i < 16; i++) {
            float4 vv = vr[i];
            a[i].x = a[i].x*sc + e*vv.x;
            a[i].y = a[i].y*sc + e*vv.y;
            a[i].z = a[i].z*sc + e*vv.z;
            a[i].w = a[i].w*sc + e*vv.w;
        }
        mr = mn;
    }
    int pi = (chunk*4 + h)*NCRS + row;
    pm[pi] = mr; pl[pi] = lr;
    float4* po = (float4*)(pacc + (size_t)pi*64);
#pragma unroll
    for (int i = 0; i < 16; i++) po[i] = a[i];
}

__global__ __launch_bounds__(256) void attn_combine(
    const float* __restrict__ pm, const float* __restrict__ pl,
    const float* __restrict__ pacc, float* __restrict__ msg)
{
    int row = blockIdx.x, t = threadIdx.x;
    int h = t >> 6, d = t & 63;
    float m = -INFINITY;
#pragma unroll
    for (int c = 0; c < NCHUNK; c++) m = fmaxf(m, pm[(c*4 + h)*NCRS + row]);
    float lsum = 0.f, asum = 0.f;
#pragma unroll
    for (int c = 0; c < NCHUNK; c++) {
        int pi = (c*4 + h)*NCRS + row;
        float w = __expf(pm[pi] - m);
        lsum += pl[pi] * w;
        asum += pacc[(size_t)pi*64 + d] * w;
    }
    msg[(size_t)row*GD + h*64 + d] = asum / lsum;
}

// out = x + [x, msg] @ Wm + bm, row-tiled
__global__ __launch_bounds__(256) void cross_combine(
    const float* __restrict__ x, const float* __restrict__ msg,
    const float* __restrict__ Wm, const float* __restrict__ bm,
    float* __restrict__ out)
{
    int t = threadIdx.x, n0 = blockIdx.x * LROWS;
    __shared__ float xs[GD][LROWS], ms[GD][LROWS];
    for (int i = t; i < LROWS*GD; i += 256) {
        int r = i >> 8, c = i & 255;
        xs[c][r] = x[(size_t)(n0+r)*GD + c];
        ms[c][r] = msg[(size_t)(n0+r)*GD + c];
    }
    __syncthreads();
    float a[LROWS];
#pragma unroll
    for (int r = 0; r < LROWS; r++) a[r] = bm[t];
    for (int c = 0; c < GD; c++) {
        float w1 = Wm[c*GD + t];
        float w2 = Wm[(GD + c)*GD + t];
        float4 x0 = *(const float4*)&xs[c][0];
        float4 x1 = *(const float4*)&xs[c][4];
        float4 m0 = *(const float4*)&ms[c][0];
        float4 m1 = *(const float4*)&ms[c][4];
        a[0] += x0.x*w1 + m0.x*w2; a[1] += x0.y*w1 + m0.y*w2;
        a[2] += x0.z*w1 + m0.z*w2; a[3] += x0.w*w1 + m0.w*w2;
        a[4] += x1.x*w1 + m1.x*w2; a[5] += x1.y*w1 + m1.y*w2;
        a[6] += x1.z*w1 + m1.z*w2; a[7] += x1.w*w1 + m1.w*w2;
    }
#pragma unroll
    for (int r = 0; r < LROWS; r++)
        out[(size_t)(n0+r)*GD + t] = xs[t][r] + a[r];
}

// =====================================================================
// proj + l2norm + score (unchanged)
// =====================================================================
__global__ __launch_bounds__(256) void proj_fused(
    const float* __restrict__ g3, const float* __restrict__ Wp,
    const float* __restrict__ bp, const float* __restrict__ Wsc,
    const float* __restrict__ bsc, float* __restrict__ feats,
    float* __restrict__ fnorm, float* __restrict__ scores)
{
    int n = blockIdx.x, t = threadIdx.x;
    __shared__ float xi[GD];
    __shared__ float red[256];
    xi[t] = g3[(size_t)n*GD + t];
    __syncthreads();
    float acc = bp[t];
    for (int c = 0; c < GD; c++) acc += xi[c] * Wp[c*GD + t];
    feats[(size_t)n*GD + t] = acc;
    red[t] = acc * acc; __syncthreads();
    for (int s = 128; s > 0; s >>= 1) { if (t < s) red[t] += red[t+s]; __syncthreads(); }
    float nrm = fmaxf(sqrtf(red[0]), 1e-12f);
    __syncthreads();
    fnorm[(size_t)n*GD + t] = acc / nrm;
    red[t] = acc * Wsc[t]; __syncthreads();
    for (int s = 128; s > 0; s >>= 1) { if (t < s) red[t] += red[t+s]; __syncthreads(); }
    if (t == 0) scores[n] = red[0] + bsc[0];
}

// ip, 4 rows per block
__global__ __launch_bounds__(256) void ip_kernel(
    const float* __restrict__ fnorm, float* __restrict__ ip)
{
    int t = threadIdx.x, n0 = blockIdx.x * 4;
    __shared__ float xs[GD][4];
    for (int i = t; i < 4*GD; i += 256) {
        int r = i >> 8, c = i & 255;
        xs[c][r] = fnorm[(size_t)(n0+r)*GD + c];
    }
    __syncthreads();
    const float4* ft = (const float4*)(fnorm + (size_t)NSRC*GD);
    for (int m = t; m < NSRC; m += 256) {
        const float4* fr = ft + (size_t)m*(GD/4);
        float a0 = 0.f, a1 = 0.f, a2 = 0.f, a3 = 0.f;
        for (int c4 = 0; c4 < GD/4; c4++) {
            float4 f = fr[c4];
            float4 xa = *(const float4*)&xs[c4*4+0][0];
            float4 xb = *(const float4*)&xs[c4*4+1][0];
            float4 xc = *(const float4*)&xs[c4*4+2][0];
            float4 xd = *(const float4*)&xs[c4*4+3][0];
            a0 += f.x*xa.x + f.y*xb.x + f.z*xc.x + f.w*xd.x;
            a1 += f.x*xa.y + f.y*xb.y + f.z*xc.y + f.w*xd.y;
            a2 += f.x*xa.z + f.y*xb.z + f.z*xc.z + f.w*xd.z;
            a3 += f.x*xa.w + f.y*xb.w + f.z*xc.w + f.w*xd.w;
        }
        ip[(size_t)(n0+0)*NSRC + m] = a0;
        ip[(size_t)(n0+1)*NSRC + m] = a1;
        ip[(size_t)(n0+2)*NSRC + m] = a2;
        ip[(size_t)(n0+3)*NSRC + m] = a3;
    }
}

// saliency (unchanged)
template<bool COL>
__global__ __launch_bounds__(256) void saliency_kernel(
    const float* __restrict__ ip, const float* __restrict__ scores_other,
    const float* __restrict__ epsv, float* __restrict__ sal_out)
{
    int n = blockIdx.x, t = threadIdx.x;
    float T = expf(epsv[0]) + 0.03f;
    __shared__ float red[256];
    float vals[4];
    float m = -INFINITY;
#pragma unroll
    for (int ii = 0; ii < 4; ii++) {
        int i = t + ii*256;
        float vv = COL ? ip[(size_t)i*NSRC + n] : ip[(size_t)n*NSRC + i];
        vv /= T;
        vals[ii] = vv;
        m = fmaxf(m, vv);
    }
    red[t] = m; __syncthreads();
    for (int s = 128; s > 0; s >>= 1) { if (t < s) red[t] = fmaxf(red[t], red[t+s]); __syncthreads(); }
    float mx = red[0]; __syncthreads();
    float se = 0.f, wsum = 0.f;
#pragma unroll
    for (int ii = 0; ii < 4; ii++) {
        int i = t + ii*256;
        float e = expf(vals[ii] - mx);
        se += e; wsum += e * scores_other[i];
    }
    red[t] = se; __syncthreads();
    for (int s = 128; s > 0; s >>= 1) { if (t < s) red[t] += red[t+s]; __syncthreads(); }
    float S = red[0]; __syncthreads();
    red[t] = wsum; __syncthreads();
    for (int s = 128; s > 0; s >>= 1) { if (t < s) red[t] += red[t+s]; __syncthreads(); }
    if (t == 0) sal_out[n] = red[0] / S;
}

// =====================================================================
// decoder — thread per row, W via wave-uniform loads, acc in registers.
// =====================================================================
__global__ __launch_bounds__(256) void decoder_kernel(
    const float* __restrict__ feats, const float* __restrict__ scores,
    const float* __restrict__ sal, const float* __restrict__ skip,
    const int* __restrict__ ups, const float* __restrict__ Wd,
    const float* __restrict__ bd, float* __restrict__ outf,
    float* __restrict__ outso, float* __restrict__ outss)
{
    int row = blockIdx.x * 256 + threadIdx.x;
    if (row >= NFINE) return;
    int u = ups[row];
    float acc[DECOUT];
#pragma unroll
    for (int j = 0; j < DECOUT; j++) acc[j] = bd[j];
    float x0 = scores[u], x1 = sal[u];
#pragma unroll
    for (int j = 0; j < DECOUT; j++) acc[j] += x0 * Wd[j];
#pragma unroll
    for (int j = 0; j < DECOUT; j++) acc[j] += x1 * Wd[DECOUT + j];
    const float4* fr = (const float4*)(feats + (size_t)u * GD);
    for (int c4 = 0; c4 < GD/4; c4++) {
        float4 xv = fr[c4];
        const float* wr = Wd + (size_t)(2 + c4*4) * DECOUT;
#pragma unroll
        for (int j = 0; j < DECOUT; j++) acc[j] += xv.x * wr[j];
#pragma unroll
        for (int j = 0; j < DECOUT; j++) acc[j] += xv.y * wr[DECOUT + j];
#pragma unroll
        for (int j = 0; j < DECOUT; j++) acc[j] += xv.z * wr[2*DECOUT + j];
#pragma unroll
        for (int j = 0; j < DECOUT; j++) acc[j] += xv.w * wr[3*DECOUT + j];
    }
    const float4* sr = (const float4*)(skip + (size_t)row * C1D);
    for (int c4 = 0; c4 < C1D/4; c4++) {
        float4 xv = sr[c4];
        const float* wr = Wd + (size_t)(2 + GD + c4*4) * DECOUT;
#pragma unroll
        for (int j = 0; j < DECOUT; j++) acc[j] += xv.x * wr[j];
#pragma unroll
        for (int j = 0; j < DECOUT; j++) acc[j] += xv.y * wr[DECOUT + j];
#pragma unroll
        for (int j = 0; j < DECOUT; j++) acc[j] += xv.z * wr[2*DECOUT + j];
#pragma unroll
        for (int j = 0; j < DECOUT; j++) acc[j] += xv.w * wr[3*DECOUT + j];
    }
    float sq = 0.f;
#pragma unroll
    for (int j = 0; j < FINALD; j++) sq += acc[j]*acc[j];
    float inv = 1.f / fmaxf(sqrtf(sq), 1e-12f);
    float4* op = (float4*)(outf + (size_t)row * FINALD);
#pragma unroll
    for (int i = 0; i < 8; i++)
        op[i] = make_float4(acc[4*i]*inv, acc[4*i+1]*inv, acc[4*i+2]*inv, acc[4*i+3]*inv);
    float so = 1.f/(1.f + __expf(-acc[32]));
    so = fminf(fmaxf(so, 0.f), 1.f); if (!(so == so)) so = 0.f;
    float ss = 1.f/(1.f + __expf(-acc[33]));
    ss = fminf(fmaxf(ss, 0.f), 1.f); if (!(ss == ss)) ss = 0.f;
    outso[row] = so; outss[row] = ss;
}

// =====================================================================
extern "C" void kernel_launch(void* const* d_in, const int* in_sizes, int n_in,
                              void* d_out, int out_size, void* d_ws, size_t ws_size,
                              hipStream_t stream)
{
    const float* points_f     = (const float*)d_in[0];
    const float* points_c     = (const float*)d_in[1];
    const float* features     = (const float*)d_in[2];
    const float* kp_f         = (const float*)d_in[3];
    const float* kp_c         = (const float*)d_in[4];
    const float* W_kp1        = (const float*)d_in[5];
    const float* W_kp2        = (const float*)d_in[6];
    const float* W_bottle     = (const float*)d_in[7];
    const float* b_bottle     = (const float*)d_in[8];
    const float* W_self1      = (const float*)d_in[9];
    const float* b_self1      = (const float*)d_in[10];
    const float* Wq           = (const float*)d_in[11];
    const float* Wk           = (const float*)d_in[12];
    const float* Wv           = (const float*)d_in[13];
    const float* W_cross      = (const float*)d_in[14];
    const float* b_cross      = (const float*)d_in[15];
    const float* W_self2      = (const float*)d_in[16];
    const float* b_self2      = (const float*)d_in[17];
    const float* W_proj       = (const float*)d_in[18];
    const float* b_proj       = (const float*)d_in[19];
    const float* W_score      = (const float*)d_in[20];
    const float* b_score      = (const float*)d_in[21];
    const float* epsilon      = (const float*)d_in[22];
    const float* W_dec        = (const float*)d_in[23];
    const float* b_dec        = (const float*)d_in[24];
    const int*   neighbors_f  = (const int*)d_in[25];
    const int*   pool_idx     = (const int*)d_in[26];
    const int*   upsample_idx = (const int*)d_in[27];

    float* ws = (float*)d_ws;
    size_t o = 0;
    auto alloc = [&](size_t nfl) { float* p = ws + o; o += (nfl + 63) & ~(size_t)63; return p; };
    float* x_f    = alloc((size_t)NFINE * C1D);
    float* g1     = alloc((size_t)NCRS * GD);
    float* qb     = alloc((size_t)NCRS * GD);
    float* kb     = alloc((size_t)NCRS * GD);
    float* vb     = alloc((size_t)NCRS * GD);
    float* msg    = alloc((size_t)NCRS * GD);
    float* scores = alloc(NCRS);
    float* sal    = alloc(NCRS);
    int*   knn_b  = (int*)alloc(NCRS * DGK);
    // union: layout A (pipeline tensors) / layout B (attn partials).
    // A tensors are all dead during [attn_partial, attn_combine).
    size_t uA = (size_t)NCRS*C2D + (size_t)NCRS*GD*5 + (size_t)NSRC*NSRC;
    size_t uB = (size_t)2*NCRS*4*NCHUNK + (size_t)NCRS*4*NCHUNK*64;
    float* ub = alloc(uA > uB ? uA : uB);
    float* x_c     = ub;
    float* feats_c = x_c + (size_t)NCRS*C2D;
    float* g2      = feats_c + (size_t)NCRS*GD;
    float* g3      = g2 + (size_t)NCRS*GD;
    float* feats   = g3 + (size_t)NCRS*GD;
    float* fnorm   = feats + (size_t)NCRS*GD;
    float* ip      = fnorm + (size_t)NCRS*GD;
    float* pm      = ub;
    float* pl      = pm + (size_t)NCRS*4*NCHUNK;
    float* pacc    = pl + (size_t)NCRS*4*NCHUNK;

    float* outf  = (float*)d_out;
    float* outso = outf + (size_t)NFINE * FINALD;
    float* outss = outso + NFINE;

    // encoder
    kpconv_fine<<<NFINE/4, 256, 0, stream>>>(points_f, features, neighbors_f, kp_f, W_kp1, x_f);
    kpconv_coarse<<<NCRS/CTILE, 256, 0, stream>>>(points_c, points_f, x_f, pool_idx, kp_c, W_kp2, x_c);
    linear_rows<C2D, GD, true><<<NCRS/LROWS, GD, 0, stream>>>(x_c, W_bottle, b_bottle, feats_c);

    // GNN
    knn_kernel<<<8, 256, 0, stream>>>(points_c, knn_b);
    self_layer_kernel<<<NSRC, 256, 0, stream>>>(feats_c, knn_b, W_self1, b_self1, g1);
    self_layer_kernel<<<NSRC, 256, 0, stream>>>(feats_c + (size_t)NSRC*GD, knn_b + NSRC*DGK,
                                                W_self1, b_self1, g1 + (size_t)NSRC*GD);
    qkv_kernel<<<NCRS/LROWS, 256, 0, stream>>>(g1, Wq, Wk, Wv, qb, kb, vb);
    attn_partial<<<(NCRS*4*NCHUNK)/256, 256, 0, stream>>>(qb, kb, vb, pm, pl, pacc);
    attn_combine<<<NCRS, 256, 0, stream>>>(pm, pl, pacc, msg);
    cross_combine<<<NCRS/LROWS, 256, 0, stream>>>(g1, msg, W_cross, b_cross, g2);
    self_layer_kernel<<<NSRC, 256, 0, stream>>>(g2, knn_b, W_self2, b_self2, g3);
    self_layer_kernel<<<NSRC, 256, 0, stream>>>(g2 + (size_t)NSRC*GD, knn_b + NSRC*DGK,
                                                W_self2, b_self2, g3 + (size_t)NSRC*GD);

    // head
    proj_fused<<<NCRS, 256, 0, stream>>>(g3, W_proj, b_proj, W_score, b_score, feats, fnorm, scores);
    ip_kernel<<<NSRC/4, 256, 0, stream>>>(fnorm, ip);
    saliency_kernel<false><<<NSRC, 256, 0, stream>>>(ip, scores + NSRC, epsilon, sal);
    saliency_kernel<true><<<NSRC, 256, 0, stream>>>(ip, scores, epsilon, sal + NSRC);

    // decoder
    decoder_kernel<<<(NFINE + 255)/256, 256, 0, stream>>>(feats, scores, sal, x_f, upsample_idx,
                                                          W_dec, b_dec, outf, outso, outss);
}

// Round 3
// 803.463 us; speedup vs baseline: 2.3124x; 1.3738x over previous
//
#include <hip/hip_runtime.h>
#include <math.h>

// ---- problem constants ----
#define NFINE   80000
#define NCRS    2048
#define NSRC    1024
#define NNB     30
#define KP      15
#define C1D     128
#define C2D     256
#define GD      256
#define DGK     10
#define FINALD  32
#define DECIN   386
#define DECOUT  34

#define NCHUNK  8      // attention key-split
#define CHUNK   128    // 1024 / NCHUNK
#define CTILE   4      // coarse points per block in kpconv_coarse
#define LROWS   8      // row tile for linear-ish kernels
#define SROWS   2      // row tile for self_layer

// =====================================================================
// Stage 1: kpconv fine — one wave per point, 4 points per block.
// =====================================================================
__global__ __launch_bounds__(256) void kpconv_fine(
    const float* __restrict__ pts, const float* __restrict__ feat,
    const int* __restrict__ nbr, const float* __restrict__ kp,
    const float* __restrict__ W, float* __restrict__ out)
{
    int t = threadIdx.x, w = t >> 6, lane = t & 63;
    int n = blockIdx.x * 4 + w;
    __shared__ float contrib[4][NNB][KP + 1];
    __shared__ float h[4][KP + 1];
    float kx[KP], ky[KP], kz[KP], kk[KP];
#pragma unroll
    for (int k = 0; k < KP; k++) {
        kx[k] = kp[k*3]; ky[k] = kp[k*3+1]; kz[k] = kp[k*3+2];
        kk[k] = kx[k]*kx[k] + ky[k]*ky[k] + kz[k]*kz[k];
    }
    if (lane < NNB) {
        float qx = pts[n*3], qy = pts[n*3+1], qz = pts[n*3+2];
        int id = nbr[n*NNB + lane];
        float rx = pts[id*3]-qx, ry = pts[id*3+1]-qy, rz = pts[id*3+2]-qz;
        float rr = rx*rx + ry*ry + rz*rz;
        float f = feat[id];
#pragma unroll
        for (int k = 0; k < KP; k++) {
            float d2 = rr + kk[k] - 2.f*(rx*kx[k] + ry*ky[k] + rz*kz[k]);
            float infl = fmaxf(1.f - sqrtf(fmaxf(d2, 1e-12f)), 0.f); // extent=1
            contrib[w][lane][k] = infl * f;
        }
    }
    __syncthreads();
    if (lane < KP) {
        float s = 0.f;
#pragma unroll
        for (int j = 0; j < NNB; j++) s += contrib[w][j][lane];
        h[w][lane] = s;
    }
    __syncthreads();
    float a0 = 0.f, a1 = 0.f;
#pragma unroll
    for (int k = 0; k < KP; k++) {
        float hk = h[w][k];
        a0 += hk * W[k*C1D + lane];
        a1 += hk * W[k*C1D + 64 + lane];
    }
    out[(size_t)n*C1D + lane]      = a0;
    out[(size_t)n*C1D + 64 + lane] = a1;
}

// =====================================================================
// Stage 2: kpconv coarse — CTILE=4 points per block; hh laid out
// [1920][4] so the W pass reads one broadcast float4 per W element.
// =====================================================================
__global__ __launch_bounds__(256) void kpconv_coarse(
    const float* __restrict__ pc, const float* __restrict__ pf,
    const float* __restrict__ xf, const int* __restrict__ pool,
    const float* __restrict__ kp, const float* __restrict__ W,
    float* __restrict__ out)
{
    int t = threadIdx.x;
    int n0 = blockIdx.x * CTILE;
    __shared__ float kx[KP], ky[KP], kz[KP], kk[KP];
    __shared__ float rel[NNB][4];
    __shared__ int   ids[NNB];
    __shared__ float infl[NNB][KP];
    __shared__ float nf[NNB][C1D];
    __shared__ float hh[KP*C1D][CTILE];   // 30720 B
    if (t < KP) {
        float a = kp[t*3], b = kp[t*3+1], c = kp[t*3+2];
        kx[t] = a; ky[t] = b; kz[t] = c; kk[t] = a*a + b*b + c*c;
    }
    for (int p = 0; p < CTILE; p++) {
        int n = n0 + p;
        __syncthreads();   // previous iteration readers done / kpt visible
        if (t < NNB) {
            int id = pool[n*NNB + t]; ids[t] = id;
            float qx = pc[n*3], qy = pc[n*3+1], qz = pc[n*3+2];
            float rx = pf[id*3]-qx, ry = pf[id*3+1]-qy, rz = pf[id*3+2]-qz;
            rel[t][0] = rx; rel[t][1] = ry; rel[t][2] = rz;
            rel[t][3] = rx*rx + ry*ry + rz*rz;
        }
        __syncthreads();
        for (int i = t; i < NNB*KP; i += 256) {
            int j = i / KP, kq = i % KP;
            float d2 = rel[j][3] + kk[kq]
                     - 2.f*(rel[j][0]*kx[kq] + rel[j][1]*ky[kq] + rel[j][2]*kz[kq]);
            infl[j][kq] = fmaxf(1.f - sqrtf(fmaxf(d2, 1e-12f)) * 0.5f, 0.f); // extent=2
        }
        for (int i = t; i < NNB*C1D; i += 256) {
            int j = i >> 7, c = i & 127;
            nf[j][c] = xf[(size_t)ids[j]*C1D + c];
        }
        __syncthreads();
        for (int i = t; i < KP*C1D; i += 256) {
            int kq = i >> 7, c = i & 127;
            float s = 0.f;
#pragma unroll
            for (int j = 0; j < NNB; j++) s += infl[j][kq] * nf[j][c];
            hh[i][p] = s;
        }
    }
    __syncthreads();
    float a0 = 0.f, a1 = 0.f, a2 = 0.f, a3 = 0.f;
    for (int i = 0; i < KP*C1D; i++) {
        float w = W[(size_t)i*C2D + t];
        float4 h4 = *(const float4*)&hh[i][0];   // broadcast
        a0 += h4.x*w; a1 += h4.y*w; a2 += h4.z*w; a3 += h4.w*w;
    }
    out[(size_t)(n0+0)*C2D + t] = a0;
    out[(size_t)(n0+1)*C2D + t] = a1;
    out[(size_t)(n0+2)*C2D + t] = a2;
    out[(size_t)(n0+3)*C2D + t] = a3;
}

// =====================================================================
// Row-tiled linear: LROWS rows per block, W read once per block.
// =====================================================================
template<int CIN, int COUT, bool BIAS>
__global__ __launch_bounds__(COUT) void linear_rows(
    const float* __restrict__ in, const float* __restrict__ W,
    const float* __restrict__ b, float* __restrict__ out)
{
    int t = threadIdx.x, n0 = blockIdx.x * LROWS;
    __shared__ float xi[CIN][LROWS];
    for (int i = t; i < LROWS*CIN; i += COUT) {
        int r = i / CIN, c = i % CIN;
        xi[c][r] = in[(size_t)(n0+r)*CIN + c];
    }
    __syncthreads();
    float a[LROWS];
#pragma unroll
    for (int r = 0; r < LROWS; r++) a[r] = BIAS ? b[t] : 0.f;
    for (int c = 0; c < CIN; c++) {
        float wv = W[c*COUT + t];
        float4 x0 = *(const float4*)&xi[c][0];
        float4 x1 = *(const float4*)&xi[c][4];
        a[0] += x0.x*wv; a[1] += x0.y*wv; a[2] += x0.z*wv; a[3] += x0.w*wv;
        a[4] += x1.x*wv; a[5] += x1.y*wv; a[6] += x1.z*wv; a[7] += x1.w*wv;
    }
#pragma unroll
    for (int r = 0; r < LROWS; r++) out[(size_t)(n0+r)*COUT + t] = a[r];
}

// fused q,k,v projections (shares staged input rows)
__global__ __launch_bounds__(256) void qkv_kernel(
    const float* __restrict__ x, const float* __restrict__ Wq,
    const float* __restrict__ Wk, const float* __restrict__ Wv,
    float* __restrict__ qb, float* __restrict__ kb, float* __restrict__ vb)
{
    int t = threadIdx.x, n0 = blockIdx.x * LROWS;
    __shared__ float xi[GD][LROWS];
    for (int i = t; i < LROWS*GD; i += 256) {
        int r = i >> 8, c = i & 255;
        xi[c][r] = x[(size_t)(n0+r)*GD + c];
    }
    __syncthreads();
    const float* Ws[3] = {Wq, Wk, Wv};
    float* outs[3] = {qb, kb, vb};
#pragma unroll
    for (int m = 0; m < 3; m++) {
        const float* W = Ws[m];
        float a[LROWS];
#pragma unroll
        for (int r = 0; r < LROWS; r++) a[r] = 0.f;
        for (int c = 0; c < GD; c++) {
            float wv = W[c*GD + t];
            float4 x0 = *(const float4*)&xi[c][0];
            float4 x1 = *(const float4*)&xi[c][4];
            a[0] += x0.x*wv; a[1] += x0.y*wv; a[2] += x0.z*wv; a[3] += x0.w*wv;
            a[4] += x1.x*wv; a[5] += x1.y*wv; a[6] += x1.z*wv; a[7] += x1.w*wv;
        }
        float* o = outs[m];
#pragma unroll
        for (int r = 0; r < LROWS; r++) o[(size_t)(n0+r)*GD + t] = a[r];
    }
}

// =====================================================================
// knn — block per query. d2 for all 1024 candidates into LDS, then 10
// deterministic min-selection rounds (lexicographic (val, idx) min).
// =====================================================================
__global__ __launch_bounds__(256) void knn_kernel(
    const float* __restrict__ pts, int* __restrict__ knn)
{
    int g = blockIdx.x;            // query 0..2047
    int t = threadIdx.x;
    int base = (g < NSRC) ? 0 : NSRC;
    int local = g - base;
    const float* P = pts + (size_t)base*3;
    __shared__ float d2s[NSRC];
    __shared__ float wval[4];
    __shared__ int   widx[4];
    float qx = P[local*3], qy = P[local*3+1], qz = P[local*3+2];
    float sqn = qx*qx + qy*qy + qz*qz;
#pragma unroll
    for (int ii = 0; ii < 4; ii++) {
        int m = t + ii*256;
        float px = P[m*3], py = P[m*3+1], pz = P[m*3+2];
        float sqm = px*px + py*py + pz*pz;
        d2s[m] = sqn + sqm - 2.f*(qx*px + qy*py + qz*pz);
    }
    __syncthreads();
    for (int r = 0; r < DGK; r++) {
        float bv = 3.4e38f; int bidx = NSRC;
#pragma unroll
        for (int ii = 0; ii < 4; ii++) {
            int m = t + ii*256;
            float v = d2s[m];
            if (v < bv) { bv = v; bidx = m; }   // ascending m: ties keep lower
        }
#pragma unroll
        for (int off = 32; off >= 1; off >>= 1) {
            float ov = __shfl_xor(bv, off);
            int   oi = __shfl_xor(bidx, off);
            if (ov < bv || (ov == bv && oi < bidx)) { bv = ov; bidx = oi; }
        }
        if ((t & 63) == 0) { wval[t >> 6] = bv; widx[t >> 6] = bidx; }
        __syncthreads();
        if (t == 0) {
            float fv = wval[0]; int fi = widx[0];
#pragma unroll
            for (int wv2 = 1; wv2 < 4; wv2++)
                if (wval[wv2] < fv || (wval[wv2] == fv && widx[wv2] < fi)) {
                    fv = wval[wv2]; fi = widx[wv2];
                }
            knn[g*DGK + r] = fi;
            d2s[fi] = 3.4e38f;
        }
        __syncthreads();
    }
}

// =====================================================================
// self_layer — SROWS=2 points per block; W read once per block for both.
// xd transposed [p][c][j] (padded 12) for float4 broadcast LDS reads.
// =====================================================================
__global__ __launch_bounds__(256) void self_layer_kernel(
    const float* __restrict__ x, const int* __restrict__ idx,
    const float* __restrict__ W, const float* __restrict__ b,
    float* __restrict__ out)
{
    int t = threadIdx.x, n0 = blockIdx.x * SROWS;
    __shared__ float xc[SROWS][GD];
    __shared__ float xd[SROWS][GD][12];
#pragma unroll
    for (int p = 0; p < SROWS; p++) xc[p][t] = x[(size_t)(n0+p)*GD + t];
    __syncthreads();
    for (int i = t; i < SROWS*DGK*GD; i += 256) {
        int p = i / (DGK*GD), rem = i % (DGK*GD);
        int j = rem >> 8, c = rem & 255;
        xd[p][c][j] = x[(size_t)idx[(n0+p)*DGK + j]*GD + c] - xc[p][c];
    }
    __syncthreads();
    float base0 = b[t], base1 = base0;
    float s0[12], s1[12];
#pragma unroll
    for (int j = 0; j < 12; j++) { s0[j] = 0.f; s1[j] = 0.f; }
    for (int c = 0; c < GD; c++) {
        float w1 = W[c*GD + t];
        float w2 = W[(GD + c)*GD + t];
        base0 += xc[0][c] * w1;
        base1 += xc[1][c] * w1;
        float4 a0 = *(const float4*)&xd[0][c][0];
        float4 a1 = *(const float4*)&xd[0][c][4];
        float4 a2 = *(const float4*)&xd[0][c][8];
        s0[0] += a0.x*w2; s0[1] += a0.y*w2; s0[2] += a0.z*w2; s0[3]  += a0.w*w2;
        s0[4] += a1.x*w2; s0[5] += a1.y*w2; s0[6] += a1.z*w2; s0[7]  += a1.w*w2;
        s0[8] += a2.x*w2; s0[9] += a2.y*w2; s0[10]+= a2.z*w2; s0[11] += a2.w*w2;
        float4 b0 = *(const float4*)&xd[1][c][0];
        float4 b1 = *(const float4*)&xd[1][c][4];
        float4 b2 = *(const float4*)&xd[1][c][8];
        s1[0] += b0.x*w2; s1[1] += b0.y*w2; s1[2] += b0.z*w2; s1[3]  += b0.w*w2;
        s1[4] += b1.x*w2; s1[5] += b1.y*w2; s1[6] += b1.z*w2; s1[7]  += b1.w*w2;
        s1[8] += b2.x*w2; s1[9] += b2.y*w2; s1[10]+= b2.z*w2; s1[11] += b2.w*w2;
    }
    float acc0 = 0.f, acc1 = 0.f;
#pragma unroll
    for (int j = 0; j < DGK; j++) {
        acc0 = fmaxf(acc0, fmaxf(base0 + s0[j], 0.f));
        acc1 = fmaxf(acc1, fmaxf(base1 + s1[j], 0.f));
    }
    out[(size_t)(n0+0)*GD + t] = acc0;
    out[(size_t)(n0+1)*GD + t] = acc1;
}

// =====================================================================
// attention: split-K flash. thread = (row, head, chunk). q/acc in regs,
// K/V rows wave-broadcast. Then merge partials.
// =====================================================================
__global__ __launch_bounds__(256, 1) void attn_partial(
    const float* __restrict__ qb, const float* __restrict__ kb,
    const float* __restrict__ vb, float* __restrict__ pm,
    float* __restrict__ pl, float* __restrict__ pacc)
{
    int g = blockIdx.x * 256 + threadIdx.x;
    int row = g & (NCRS - 1);
    int h = (g >> 11) & 3;
    int chunk = g >> 13;
    int kbase = (row < NSRC) ? NSRC : 0;

    const float4* q4 = (const float4*)(qb + (size_t)row*GD + h*64);
    float4 q[16];
#pragma unroll
    for (int i = 0; i < 16; i++) q[i] = q4[i];
    float4 a[16];
#pragma unroll
    for (int i = 0; i < 16; i++) a[i] = make_float4(0.f, 0.f, 0.f, 0.f);
    float mr = -INFINITY, lr = 0.f;

    const float* kbp = kb + ((size_t)(kbase + chunk*CHUNK))*GD + h*64;
    const float* vbp = vb + ((size_t)(kbase + chunk*CHUNK))*GD + h*64;
    for (int j = 0; j < CHUNK; j++) {
        const float4* kr = (const float4*)(kbp + (size_t)j*GD);
        float d0 = 0.f, d1 = 0.f, d2 = 0.f, d3 = 0.f;
#pragma unroll
        for (int i = 0; i < 16; i += 4) {
            float4 k0 = kr[i], k1 = kr[i+1], k2 = kr[i+2], k3 = kr[i+3];
            d0 += q[i].x*k0.x + q[i].y*k0.y + q[i].z*k0.z + q[i].w*k0.w;
            d1 += q[i+1].x*k1.x + q[i+1].y*k1.y + q[i+1].z*k1.z + q[i+1].w*k1.w;
            d2 += q[i+2].x*k2.x + q[i+2].y*k2.y + q[i+2].z*k2.z + q[i+2].w*k2.w;
            d3 += q[i+3].x*k3.x + q[i+3].y*k3.y + q[i+3].z*k3.z + q[i+3].w*k3.w;
        }
        float p = ((d0 + d1) + (d2 + d3)) * 0.125f;   // 1/sqrt(64)
        float mn = fmaxf(mr, p);
        float sc = __expf(mr - mn);
        float e  = __expf(p - mn);
        lr = lr*sc + e;
        const float4* vr = (const float4*)(vbp + (size_t)j*GD);
#pragma unroll
        for (int i = 0; i < 16; i++) {
            float4 vv = vr[i];
            a[i].x = a[i].x*sc + e*vv.x;
            a[i].y = a[i].y*sc + e*vv.y;
            a[i].z = a[i].z*sc + e*vv.z;
            a[i].w = a[i].w*sc + e*vv.w;
        }
        mr = mn;
    }
    int pi = (chunk*4 + h)*NCRS + row;
    pm[pi] = mr; pl[pi] = lr;
    float4* po = (float4*)(pacc + (size_t)pi*64);
#pragma unroll
    for (int i = 0; i < 16; i++) po[i] = a[i];
}

__global__ __launch_bounds__(256) void attn_combine(
    const float* __restrict__ pm, const float* __restrict__ pl,
    const float* __restrict__ pacc, float* __restrict__ msg)
{
    int row = blockIdx.x, t = threadIdx.x;
    int h = t >> 6, d = t & 63;
    float m = -INFINITY;
#pragma unroll
    for (int c = 0; c < NCHUNK; c++) m = fmaxf(m, pm[(c*4 + h)*NCRS + row]);
    float lsum = 0.f, asum = 0.f;
#pragma unroll
    for (int c = 0; c < NCHUNK; c++) {
        int pi = (c*4 + h)*NCRS + row;
        float w = __expf(pm[pi] - m);
        lsum += pl[pi] * w;
        asum += pacc[(size_t)pi*64 + d] * w;
    }
    msg[(size_t)row*GD + h*64 + d] = asum / lsum;
}

// out = x + [x, msg] @ Wm + bm, row-tiled
__global__ __launch_bounds__(256) void cross_combine(
    const float* __restrict__ x, const float* __restrict__ msg,
    const float* __restrict__ Wm, const float* __restrict__ bm,
    float* __restrict__ out)
{
    int t = threadIdx.x, n0 = blockIdx.x * LROWS;
    __shared__ float xs[GD][LROWS], ms[GD][LROWS];
    for (int i = t; i < LROWS*GD; i += 256) {
        int r = i >> 8, c = i & 255;
        xs[c][r] = x[(size_t)(n0+r)*GD + c];
        ms[c][r] = msg[(size_t)(n0+r)*GD + c];
    }
    __syncthreads();
    float a[LROWS];
#pragma unroll
    for (int r = 0; r < LROWS; r++) a[r] = bm[t];
    for (int c = 0; c < GD; c++) {
        float w1 = Wm[c*GD + t];
        float w2 = Wm[(GD + c)*GD + t];
        float4 x0 = *(const float4*)&xs[c][0];
        float4 x1 = *(const float4*)&xs[c][4];
        float4 m0 = *(const float4*)&ms[c][0];
        float4 m1 = *(const float4*)&ms[c][4];
        a[0] += x0.x*w1 + m0.x*w2; a[1] += x0.y*w1 + m0.y*w2;
        a[2] += x0.z*w1 + m0.z*w2; a[3] += x0.w*w1 + m0.w*w2;
        a[4] += x1.x*w1 + m1.x*w2; a[5] += x1.y*w1 + m1.y*w2;
        a[6] += x1.z*w1 + m1.z*w2; a[7] += x1.w*w1 + m1.w*w2;
    }
#pragma unroll
    for (int r = 0; r < LROWS; r++)
        out[(size_t)(n0+r)*GD + t] = xs[t][r] + a[r];
}

// =====================================================================
// proj + l2norm + score
// =====================================================================
__global__ __launch_bounds__(256) void proj_fused(
    const float* __restrict__ g3, const float* __restrict__ Wp,
    const float* __restrict__ bp, const float* __restrict__ Wsc,
    const float* __restrict__ bsc, float* __restrict__ feats,
    float* __restrict__ fnorm, float* __restrict__ scores)
{
    int n = blockIdx.x, t = threadIdx.x;
    __shared__ float xi[GD];
    __shared__ float red[256];
    xi[t] = g3[(size_t)n*GD + t];
    __syncthreads();
    float acc = bp[t];
    for (int c = 0; c < GD; c++) acc += xi[c] * Wp[c*GD + t];
    feats[(size_t)n*GD + t] = acc;
    red[t] = acc * acc; __syncthreads();
    for (int s = 128; s > 0; s >>= 1) { if (t < s) red[t] += red[t+s]; __syncthreads(); }
    float nrm = fmaxf(sqrtf(red[0]), 1e-12f);
    __syncthreads();
    fnorm[(size_t)n*GD + t] = acc / nrm;
    red[t] = acc * Wsc[t]; __syncthreads();
    for (int s = 128; s > 0; s >>= 1) { if (t < s) red[t] += red[t+s]; __syncthreads(); }
    if (t == 0) scores[n] = red[0] + bsc[0];
}

// ip, 4 rows per block
__global__ __launch_bounds__(256) void ip_kernel(
    const float* __restrict__ fnorm, float* __restrict__ ip)
{
    int t = threadIdx.x, n0 = blockIdx.x * 4;
    __shared__ float xs[GD][4];
    for (int i = t; i < 4*GD; i += 256) {
        int r = i >> 8, c = i & 255;
        xs[c][r] = fnorm[(size_t)(n0+r)*GD + c];
    }
    __syncthreads();
    const float4* ft = (const float4*)(fnorm + (size_t)NSRC*GD);
    for (int m = t; m < NSRC; m += 256) {
        const float4* fr = ft + (size_t)m*(GD/4);
        float a0 = 0.f, a1 = 0.f, a2 = 0.f, a3 = 0.f;
        for (int c4 = 0; c4 < GD/4; c4++) {
            float4 f = fr[c4];
            float4 xa = *(const float4*)&xs[c4*4+0][0];
            float4 xb = *(const float4*)&xs[c4*4+1][0];
            float4 xc = *(const float4*)&xs[c4*4+2][0];
            float4 xd = *(const float4*)&xs[c4*4+3][0];
            a0 += f.x*xa.x + f.y*xb.x + f.z*xc.x + f.w*xd.x;
            a1 += f.x*xa.y + f.y*xb.y + f.z*xc.y + f.w*xd.y;
            a2 += f.x*xa.z + f.y*xb.z + f.z*xc.z + f.w*xd.z;
            a3 += f.x*xa.w + f.y*xb.w + f.z*xc.w + f.w*xd.w;
        }
        ip[(size_t)(n0+0)*NSRC + m] = a0;
        ip[(size_t)(n0+1)*NSRC + m] = a1;
        ip[(size_t)(n0+2)*NSRC + m] = a2;
        ip[(size_t)(n0+3)*NSRC + m] = a3;
    }
}

// saliency
template<bool COL>
__global__ __launch_bounds__(256) void saliency_kernel(
    const float* __restrict__ ip, const float* __restrict__ scores_other,
    const float* __restrict__ epsv, float* __restrict__ sal_out)
{
    int n = blockIdx.x, t = threadIdx.x;
    float T = expf(epsv[0]) + 0.03f;
    __shared__ float red[256];
    float vals[4];
    float m = -INFINITY;
#pragma unroll
    for (int ii = 0; ii < 4; ii++) {
        int i = t + ii*256;
        float vv = COL ? ip[(size_t)i*NSRC + n] : ip[(size_t)n*NSRC + i];
        vv /= T;
        vals[ii] = vv;
        m = fmaxf(m, vv);
    }
    red[t] = m; __syncthreads();
    for (int s = 128; s > 0; s >>= 1) { if (t < s) red[t] = fmaxf(red[t], red[t+s]); __syncthreads(); }
    float mx = red[0]; __syncthreads();
    float se = 0.f, wsum = 0.f;
#pragma unroll
    for (int ii = 0; ii < 4; ii++) {
        int i = t + ii*256;
        float e = expf(vals[ii] - mx);
        se += e; wsum += e * scores_other[i];
    }
    red[t] = se; __syncthreads();
    for (int s = 128; s > 0; s >>= 1) { if (t < s) red[t] += red[t+s]; __syncthreads(); }
    float S = red[0]; __syncthreads();
    red[t] = wsum; __syncthreads();
    for (int s = 128; s > 0; s >>= 1) { if (t < s) red[t] += red[t+s]; __syncthreads(); }
    if (t == 0) sal_out[n] = red[0] / S;
}

// =====================================================================
// decoder — thread per row, W via wave-uniform loads, acc in registers.
// =====================================================================
__global__ __launch_bounds__(256) void decoder_kernel(
    const float* __restrict__ feats, const float* __restrict__ scores,
    const float* __restrict__ sal, const float* __restrict__ skip,
    const int* __restrict__ ups, const float* __restrict__ Wd,
    const float* __restrict__ bd, float* __restrict__ outf,
    float* __restrict__ outso, float* __restrict__ outss)
{
    int row = blockIdx.x * 256 + threadIdx.x;
    if (row >= NFINE) return;
    int u = ups[row];
    float acc[DECOUT];
#pragma unroll
    for (int j = 0; j < DECOUT; j++) acc[j] = bd[j];
    float x0 = scores[u], x1 = sal[u];
#pragma unroll
    for (int j = 0; j < DECOUT; j++) acc[j] += x0 * Wd[j];
#pragma unroll
    for (int j = 0; j < DECOUT; j++) acc[j] += x1 * Wd[DECOUT + j];
    const float4* fr = (const float4*)(feats + (size_t)u * GD);
    for (int c4 = 0; c4 < GD/4; c4++) {
        float4 xv = fr[c4];
        const float* wr = Wd + (size_t)(2 + c4*4) * DECOUT;
#pragma unroll
        for (int j = 0; j < DECOUT; j++) acc[j] += xv.x * wr[j];
#pragma unroll
        for (int j = 0; j < DECOUT; j++) acc[j] += xv.y * wr[DECOUT + j];
#pragma unroll
        for (int j = 0; j < DECOUT; j++) acc[j] += xv.z * wr[2*DECOUT + j];
#pragma unroll
        for (int j = 0; j < DECOUT; j++) acc[j] += xv.w * wr[3*DECOUT + j];
    }
    const float4* sr = (const float4*)(skip + (size_t)row * C1D);
    for (int c4 = 0; c4 < C1D/4; c4++) {
        float4 xv = sr[c4];
        const float* wr = Wd + (size_t)(2 + GD + c4*4) * DECOUT;
#pragma unroll
        for (int j = 0; j < DECOUT; j++) acc[j] += xv.x * wr[j];
#pragma unroll
        for (int j = 0; j < DECOUT; j++) acc[j] += xv.y * wr[DECOUT + j];
#pragma unroll
        for (int j = 0; j < DECOUT; j++) acc[j] += xv.z * wr[2*DECOUT + j];
#pragma unroll
        for (int j = 0; j < DECOUT; j++) acc[j] += xv.w * wr[3*DECOUT + j];
    }
    float sq = 0.f;
#pragma unroll
    for (int j = 0; j < FINALD; j++) sq += acc[j]*acc[j];
    float inv = 1.f / fmaxf(sqrtf(sq), 1e-12f);
    float4* op = (float4*)(outf + (size_t)row * FINALD);
#pragma unroll
    for (int i = 0; i < 8; i++)
        op[i] = make_float4(acc[4*i]*inv, acc[4*i+1]*inv, acc[4*i+2]*inv, acc[4*i+3]*inv);
    float so = 1.f/(1.f + __expf(-acc[32]));
    so = fminf(fmaxf(so, 0.f), 1.f); if (!(so == so)) so = 0.f;
    float ss = 1.f/(1.f + __expf(-acc[33]));
    ss = fminf(fmaxf(ss, 0.f), 1.f); if (!(ss == ss)) ss = 0.f;
    outso[row] = so; outss[row] = ss;
}

// =====================================================================
extern "C" void kernel_launch(void* const* d_in, const int* in_sizes, int n_in,
                              void* d_out, int out_size, void* d_ws, size_t ws_size,
                              hipStream_t stream)
{
    const float* points_f     = (const float*)d_in[0];
    const float* points_c     = (const float*)d_in[1];
    const float* features     = (const float*)d_in[2];
    const float* kp_f         = (const float*)d_in[3];
    const float* kp_c         = (const float*)d_in[4];
    const float* W_kp1        = (const float*)d_in[5];
    const float* W_kp2        = (const float*)d_in[6];
    const float* W_bottle     = (const float*)d_in[7];
    const float* b_bottle     = (const float*)d_in[8];
    const float* W_self1      = (const float*)d_in[9];
    const float* b_self1      = (const float*)d_in[10];
    const float* Wq           = (const float*)d_in[11];
    const float* Wk           = (const float*)d_in[12];
    const float* Wv           = (const float*)d_in[13];
    const float* W_cross      = (const float*)d_in[14];
    const float* b_cross      = (const float*)d_in[15];
    const float* W_self2      = (const float*)d_in[16];
    const float* b_self2      = (const float*)d_in[17];
    const float* W_proj       = (const float*)d_in[18];
    const float* b_proj       = (const float*)d_in[19];
    const float* W_score      = (const float*)d_in[20];
    const float* b_score      = (const float*)d_in[21];
    const float* epsilon      = (const float*)d_in[22];
    const float* W_dec        = (const float*)d_in[23];
    const float* b_dec        = (const float*)d_in[24];
    const int*   neighbors_f  = (const int*)d_in[25];
    const int*   pool_idx     = (const int*)d_in[26];
    const int*   upsample_idx = (const int*)d_in[27];

    float* ws = (float*)d_ws;
    size_t o = 0;
    auto alloc = [&](size_t nfl) { float* p = ws + o; o += (nfl + 63) & ~(size_t)63; return p; };
    float* x_f    = alloc((size_t)NFINE * C1D);
    float* g1     = alloc((size_t)NCRS * GD);
    float* qb     = alloc((size_t)NCRS * GD);
    float* kb     = alloc((size_t)NCRS * GD);
    float* vb     = alloc((size_t)NCRS * GD);
    float* msg    = alloc((size_t)NCRS * GD);
    float* scores = alloc(NCRS);
    float* sal    = alloc(NCRS);
    int*   knn_b  = (int*)alloc(NCRS * DGK);
    // union: layout A (pipeline tensors) / layout B (attn partials).
    // A tensors are all dead during [attn_partial, attn_combine).
    size_t uA = (size_t)NCRS*C2D + (size_t)NCRS*GD*5 + (size_t)NSRC*NSRC;
    size_t uB = (size_t)2*NCRS*4*NCHUNK + (size_t)NCRS*4*NCHUNK*64;
    float* ub = alloc(uA > uB ? uA : uB);
    float* x_c     = ub;
    float* feats_c = x_c + (size_t)NCRS*C2D;
    float* g2      = feats_c + (size_t)NCRS*GD;
    float* g3      = g2 + (size_t)NCRS*GD;
    float* feats   = g3 + (size_t)NCRS*GD;
    float* fnorm   = feats + (size_t)NCRS*GD;
    float* ip      = fnorm + (size_t)NCRS*GD;
    float* pm      = ub;
    float* pl      = pm + (size_t)NCRS*4*NCHUNK;
    float* pacc    = pl + (size_t)NCRS*4*NCHUNK;

    float* outf  = (float*)d_out;
    float* outso = outf + (size_t)NFINE * FINALD;
    float* outss = outso + NFINE;

    // encoder
    kpconv_fine<<<NFINE/4, 256, 0, stream>>>(points_f, features, neighbors_f, kp_f, W_kp1, x_f);
    kpconv_coarse<<<NCRS/CTILE, 256, 0, stream>>>(points_c, points_f, x_f, pool_idx, kp_c, W_kp2, x_c);
    linear_rows<C2D, GD, true><<<NCRS/LROWS, GD, 0, stream>>>(x_c, W_bottle, b_bottle, feats_c);

    // GNN
    knn_kernel<<<NCRS, 256, 0, stream>>>(points_c, knn_b);
    self_layer_kernel<<<NSRC/SROWS, 256, 0, stream>>>(feats_c, knn_b, W_self1, b_self1, g1);
    self_layer_kernel<<<NSRC/SROWS, 256, 0, stream>>>(feats_c + (size_t)NSRC*GD, knn_b + NSRC*DGK,
                                                      W_self1, b_self1, g1 + (size_t)NSRC*GD);
    qkv_kernel<<<NCRS/LROWS, 256, 0, stream>>>(g1, Wq, Wk, Wv, qb, kb, vb);
    attn_partial<<<(NCRS*4*NCHUNK)/256, 256, 0, stream>>>(qb, kb, vb, pm, pl, pacc);
    attn_combine<<<NCRS, 256, 0, stream>>>(pm, pl, pacc, msg);
    cross_combine<<<NCRS/LROWS, 256, 0, stream>>>(g1, msg, W_cross, b_cross, g2);
    self_layer_kernel<<<NSRC/SROWS, 256, 0, stream>>>(g2, knn_b, W_self2, b_self2, g3);
    self_layer_kernel<<<NSRC/SROWS, 256, 0, stream>>>(g2 + (size_t)NSRC*GD, knn_b + NSRC*DGK,
                                                      W_self2, b_self2, g3 + (size_t)NSRC*GD);

    // head
    proj_fused<<<NCRS, 256, 0, stream>>>(g3, W_proj, b_proj, W_score, b_score, feats, fnorm, scores);
    ip_kernel<<<NSRC/4, 256, 0, stream>>>(fnorm, ip);
    saliency_kernel<false><<<NSRC, 256, 0, stream>>>(ip, scores + NSRC, epsilon, sal);
    saliency_kernel<true><<<NSRC, 256, 0, stream>>>(ip, scores, epsilon, sal + NSRC);

    // decoder
    decoder_kernel<<<(NFINE + 255)/256, 256, 0, stream>>>(feats, scores, sal, x_f, upsample_idx,
                                                          W_dec, b_dec, outf, outso, outss);
}

// Round 4
// 761.132 us; speedup vs baseline: 2.4410x; 1.0556x over previous
//
#include <hip/hip_runtime.h>
#include <math.h>

// ---- problem constants ----
#define NFINE   80000
#define NCRS    2048
#define NSRC    1024
#define NNB     30
#define KP      15
#define C1D     128
#define C2D     256
#define GD      256
#define DGK     10
#define FINALD  32
#define DECIN   386
#define DECOUT  34

#define NCHUNK  8      // attention key-split
#define CHUNK   128    // 1024 / NCHUNK
#define TK      32     // attention LDS key tile
#define CTILE   8      // coarse points per block in kpconv_coarse
#define LROWS   8      // row tile for linear-ish kernels
#define SROWS   4      // row tile for self_layer

// =====================================================================
// Stage 1: kpconv fine — one wave per point, 4 points per block.
// =====================================================================
__global__ __launch_bounds__(256) void kpconv_fine(
    const float* __restrict__ pts, const float* __restrict__ feat,
    const int* __restrict__ nbr, const float* __restrict__ kp,
    const float* __restrict__ W, float* __restrict__ out)
{
    int t = threadIdx.x, w = t >> 6, lane = t & 63;
    int n = blockIdx.x * 4 + w;
    __shared__ float contrib[4][NNB][KP + 1];
    __shared__ float h[4][KP + 1];
    float kx[KP], ky[KP], kz[KP], kk[KP];
#pragma unroll
    for (int k = 0; k < KP; k++) {
        kx[k] = kp[k*3]; ky[k] = kp[k*3+1]; kz[k] = kp[k*3+2];
        kk[k] = kx[k]*kx[k] + ky[k]*ky[k] + kz[k]*kz[k];
    }
    if (lane < NNB) {
        float qx = pts[n*3], qy = pts[n*3+1], qz = pts[n*3+2];
        int id = nbr[n*NNB + lane];
        float rx = pts[id*3]-qx, ry = pts[id*3+1]-qy, rz = pts[id*3+2]-qz;
        float rr = rx*rx + ry*ry + rz*rz;
        float f = feat[id];
#pragma unroll
        for (int k = 0; k < KP; k++) {
            float d2 = rr + kk[k] - 2.f*(rx*kx[k] + ry*ky[k] + rz*kz[k]);
            float infl = fmaxf(1.f - sqrtf(fmaxf(d2, 1e-12f)), 0.f); // extent=1
            contrib[w][lane][k] = infl * f;
        }
    }
    __syncthreads();
    if (lane < KP) {
        float s = 0.f;
#pragma unroll
        for (int j = 0; j < NNB; j++) s += contrib[w][j][lane];
        h[w][lane] = s;
    }
    __syncthreads();
    float a0 = 0.f, a1 = 0.f;
#pragma unroll
    for (int k = 0; k < KP; k++) {
        float hk = h[w][k];
        a0 += hk * W[k*C1D + lane];
        a1 += hk * W[k*C1D + 64 + lane];
    }
    out[(size_t)n*C1D + lane]      = a0;
    out[(size_t)n*C1D + 64 + lane] = a1;
}

// =====================================================================
// Stage 2: kpconv coarse — CTILE=8 points per block; hh laid out
// [1920][8] so the W pass reads two broadcast float4 per W element.
// =====================================================================
__global__ __launch_bounds__(256) void kpconv_coarse(
    const float* __restrict__ pc, const float* __restrict__ pf,
    const float* __restrict__ xf, const int* __restrict__ pool,
    const float* __restrict__ kp, const float* __restrict__ W,
    float* __restrict__ out)
{
    int t = threadIdx.x;
    int n0 = blockIdx.x * CTILE;
    __shared__ float kx[KP], ky[KP], kz[KP], kk[KP];
    __shared__ float rel[NNB][4];
    __shared__ int   ids[NNB];
    __shared__ float infl[NNB][KP];
    __shared__ float nf[NNB][C1D];
    __shared__ float hh[KP*C1D][CTILE];   // 61440 B
    if (t < KP) {
        float a = kp[t*3], b = kp[t*3+1], c = kp[t*3+2];
        kx[t] = a; ky[t] = b; kz[t] = c; kk[t] = a*a + b*b + c*c;
    }
    for (int p = 0; p < CTILE; p++) {
        int n = n0 + p;
        __syncthreads();   // previous iteration readers done / kpt visible
        if (t < NNB) {
            int id = pool[n*NNB + t]; ids[t] = id;
            float qx = pc[n*3], qy = pc[n*3+1], qz = pc[n*3+2];
            float rx = pf[id*3]-qx, ry = pf[id*3+1]-qy, rz = pf[id*3+2]-qz;
            rel[t][0] = rx; rel[t][1] = ry; rel[t][2] = rz;
            rel[t][3] = rx*rx + ry*ry + rz*rz;
        }
        __syncthreads();
        for (int i = t; i < NNB*KP; i += 256) {
            int j = i / KP, kq = i % KP;
            float d2 = rel[j][3] + kk[kq]
                     - 2.f*(rel[j][0]*kx[kq] + rel[j][1]*ky[kq] + rel[j][2]*kz[kq]);
            infl[j][kq] = fmaxf(1.f - sqrtf(fmaxf(d2, 1e-12f)) * 0.5f, 0.f); // extent=2
        }
        for (int i = t; i < NNB*C1D; i += 256) {
            int j = i >> 7, c = i & 127;
            nf[j][c] = xf[(size_t)ids[j]*C1D + c];
        }
        __syncthreads();
        for (int i = t; i < KP*C1D; i += 256) {
            int kq = i >> 7, c = i & 127;
            float s = 0.f;
#pragma unroll
            for (int j = 0; j < NNB; j++) s += infl[j][kq] * nf[j][c];
            hh[i][p] = s;
        }
    }
    __syncthreads();
    float a0=0.f,a1=0.f,a2=0.f,a3=0.f,a4=0.f,a5=0.f,a6=0.f,a7=0.f;
    for (int i = 0; i < KP*C1D; i++) {
        float w = W[(size_t)i*C2D + t];
        float4 hA = *(const float4*)&hh[i][0];   // broadcast
        float4 hB = *(const float4*)&hh[i][4];
        a0 += hA.x*w; a1 += hA.y*w; a2 += hA.z*w; a3 += hA.w*w;
        a4 += hB.x*w; a5 += hB.y*w; a6 += hB.z*w; a7 += hB.w*w;
    }
    out[(size_t)(n0+0)*C2D + t] = a0;
    out[(size_t)(n0+1)*C2D + t] = a1;
    out[(size_t)(n0+2)*C2D + t] = a2;
    out[(size_t)(n0+3)*C2D + t] = a3;
    out[(size_t)(n0+4)*C2D + t] = a4;
    out[(size_t)(n0+5)*C2D + t] = a5;
    out[(size_t)(n0+6)*C2D + t] = a6;
    out[(size_t)(n0+7)*C2D + t] = a7;
}

// =====================================================================
// Row-tiled linear: LROWS rows per block, W read once per block.
// =====================================================================
template<int CIN, int COUT, bool BIAS>
__global__ __launch_bounds__(COUT) void linear_rows(
    const float* __restrict__ in, const float* __restrict__ W,
    const float* __restrict__ b, float* __restrict__ out)
{
    int t = threadIdx.x, n0 = blockIdx.x * LROWS;
    __shared__ float xi[CIN][LROWS];
    for (int i = t; i < LROWS*CIN; i += COUT) {
        int r = i / CIN, c = i % CIN;
        xi[c][r] = in[(size_t)(n0+r)*CIN + c];
    }
    __syncthreads();
    float a[LROWS];
#pragma unroll
    for (int r = 0; r < LROWS; r++) a[r] = BIAS ? b[t] : 0.f;
    for (int c = 0; c < CIN; c++) {
        float wv = W[c*COUT + t];
        float4 x0 = *(const float4*)&xi[c][0];
        float4 x1 = *(const float4*)&xi[c][4];
        a[0] += x0.x*wv; a[1] += x0.y*wv; a[2] += x0.z*wv; a[3] += x0.w*wv;
        a[4] += x1.x*wv; a[5] += x1.y*wv; a[6] += x1.z*wv; a[7] += x1.w*wv;
    }
#pragma unroll
    for (int r = 0; r < LROWS; r++) out[(size_t)(n0+r)*COUT + t] = a[r];
}

// fused q,k,v projections (shares staged input rows)
__global__ __launch_bounds__(256) void qkv_kernel(
    const float* __restrict__ x, const float* __restrict__ Wq,
    const float* __restrict__ Wk, const float* __restrict__ Wv,
    float* __restrict__ qb, float* __restrict__ kb, float* __restrict__ vb)
{
    int t = threadIdx.x, n0 = blockIdx.x * LROWS;
    __shared__ float xi[GD][LROWS];
    for (int i = t; i < LROWS*GD; i += 256) {
        int r = i >> 8, c = i & 255;
        xi[c][r] = x[(size_t)(n0+r)*GD + c];
    }
    __syncthreads();
    const float* Ws[3] = {Wq, Wk, Wv};
    float* outs[3] = {qb, kb, vb};
#pragma unroll
    for (int m = 0; m < 3; m++) {
        const float* W = Ws[m];
        float a[LROWS];
#pragma unroll
        for (int r = 0; r < LROWS; r++) a[r] = 0.f;
        for (int c = 0; c < GD; c++) {
            float wv = W[c*GD + t];
            float4 x0 = *(const float4*)&xi[c][0];
            float4 x1 = *(const float4*)&xi[c][4];
            a[0] += x0.x*wv; a[1] += x0.y*wv; a[2] += x0.z*wv; a[3] += x0.w*wv;
            a[4] += x1.x*wv; a[5] += x1.y*wv; a[6] += x1.z*wv; a[7] += x1.w*wv;
        }
        float* o = outs[m];
#pragma unroll
        for (int r = 0; r < LROWS; r++) o[(size_t)(n0+r)*GD + t] = a[r];
    }
}

// =====================================================================
// knn — block per query, LDS d2 + 10 deterministic min-selections.
// =====================================================================
__global__ __launch_bounds__(256) void knn_kernel(
    const float* __restrict__ pts, int* __restrict__ knn)
{
    int g = blockIdx.x;            // query 0..2047
    int t = threadIdx.x;
    int base = (g < NSRC) ? 0 : NSRC;
    int local = g - base;
    const float* P = pts + (size_t)base*3;
    __shared__ float d2s[NSRC];
    __shared__ float wval[4];
    __shared__ int   widx[4];
    float qx = P[local*3], qy = P[local*3+1], qz = P[local*3+2];
    float sqn = qx*qx + qy*qy + qz*qz;
#pragma unroll
    for (int ii = 0; ii < 4; ii++) {
        int m = t + ii*256;
        float px = P[m*3], py = P[m*3+1], pz = P[m*3+2];
        float sqm = px*px + py*py + pz*pz;
        d2s[m] = sqn + sqm - 2.f*(qx*px + qy*py + qz*pz);
    }
    __syncthreads();
    for (int r = 0; r < DGK; r++) {
        float bv = 3.4e38f; int bidx = NSRC;
#pragma unroll
        for (int ii = 0; ii < 4; ii++) {
            int m = t + ii*256;
            float v = d2s[m];
            if (v < bv) { bv = v; bidx = m; }   // ascending m: ties keep lower
        }
#pragma unroll
        for (int off = 32; off >= 1; off >>= 1) {
            float ov = __shfl_xor(bv, off);
            int   oi = __shfl_xor(bidx, off);
            if (ov < bv || (ov == bv && oi < bidx)) { bv = ov; bidx = oi; }
        }
        if ((t & 63) == 0) { wval[t >> 6] = bv; widx[t >> 6] = bidx; }
        __syncthreads();
        if (t == 0) {
            float fv = wval[0]; int fi = widx[0];
#pragma unroll
            for (int wv2 = 1; wv2 < 4; wv2++)
                if (wval[wv2] < fv || (wval[wv2] == fv && widx[wv2] < fi)) {
                    fv = wval[wv2]; fi = widx[wv2];
                }
            knn[g*DGK + r] = fi;
            d2s[fi] = 3.4e38f;
        }
        __syncthreads();
    }
}

// =====================================================================
// self_layer — SROWS=4 points per block; W read once per block.
// xd transposed [p][c][j] (padded 12) for float4 broadcast LDS reads.
// =====================================================================
__global__ __launch_bounds__(256) void self_layer_kernel(
    const float* __restrict__ x, const int* __restrict__ idx,
    const float* __restrict__ W, const float* __restrict__ b,
    float* __restrict__ out)
{
    int t = threadIdx.x, n0 = blockIdx.x * SROWS;
    __shared__ float xc[SROWS][GD];
    __shared__ float xd[SROWS][GD][12];
#pragma unroll
    for (int p = 0; p < SROWS; p++) xc[p][t] = x[(size_t)(n0+p)*GD + t];
    __syncthreads();
    for (int i = t; i < SROWS*DGK*GD; i += 256) {
        int p = i / (DGK*GD), rem = i % (DGK*GD);
        int j = rem >> 8, c = rem & 255;
        xd[p][c][j] = x[(size_t)idx[(n0+p)*DGK + j]*GD + c] - xc[p][c];
    }
    __syncthreads();
    float base[SROWS];
    float s[SROWS][12];
#pragma unroll
    for (int p = 0; p < SROWS; p++) {
        base[p] = b[t];
#pragma unroll
        for (int j = 0; j < 12; j++) s[p][j] = 0.f;
    }
    for (int c = 0; c < GD; c++) {
        float w1 = W[c*GD + t];
        float w2 = W[(GD + c)*GD + t];
#pragma unroll
        for (int p = 0; p < SROWS; p++) {
            base[p] += xc[p][c] * w1;
            float4 a0 = *(const float4*)&xd[p][c][0];
            float4 a1 = *(const float4*)&xd[p][c][4];
            float4 a2 = *(const float4*)&xd[p][c][8];
            s[p][0] += a0.x*w2; s[p][1] += a0.y*w2; s[p][2] += a0.z*w2; s[p][3]  += a0.w*w2;
            s[p][4] += a1.x*w2; s[p][5] += a1.y*w2; s[p][6] += a1.z*w2; s[p][7]  += a1.w*w2;
            s[p][8] += a2.x*w2; s[p][9] += a2.y*w2; s[p][10]+= a2.z*w2; s[p][11] += a2.w*w2;
        }
    }
#pragma unroll
    for (int p = 0; p < SROWS; p++) {
        float acc = 0.f;
#pragma unroll
        for (int j = 0; j < DGK; j++) acc = fmaxf(acc, fmaxf(base[p] + s[p][j], 0.f));
        out[(size_t)(n0+p)*GD + t] = acc;
    }
}

// =====================================================================
// attention: block-level flash with double-buffered LDS K/V staging.
// block = 256 rows x 1 head x 1 chunk (256 blocks). Partials merged
// by attn_combine (unchanged layout).
// =====================================================================
__global__ __launch_bounds__(256) void attn_flash(
    const float* __restrict__ qb, const float* __restrict__ kb,
    const float* __restrict__ vb, float* __restrict__ pm,
    float* __restrict__ pl, float* __restrict__ pacc)
{
    int bidx = blockIdx.x;
    int h = bidx & 3, chunk = (bidx >> 2) & 7, rb = bidx >> 5;
    int t = threadIdx.x;
    int row = rb * 256 + t;
    int kbase = (row < NSRC) ? NSRC : 0;   // uniform across block

    __shared__ float4 kt[2][TK][16];
    __shared__ float4 vt[2][TK][16];

    const float4* kb4 = (const float4*)kb;
    const float4* vb4 = (const float4*)vb;
    size_t gbase = ((size_t)(kbase + chunk*CHUNK)) * 64 + h*16;

    float4 q[16];
    const float4* q4 = (const float4*)(qb + (size_t)row*GD + h*64);
#pragma unroll
    for (int i = 0; i < 16; i++) q[i] = q4[i];
    float4 a[16];
#pragma unroll
    for (int i = 0; i < 16; i++) a[i] = make_float4(0.f, 0.f, 0.f, 0.f);
    float mr = -INFINITY, lr = 0.f;

    int f0 = t, f1 = t + 256;             // flat float4 index: key=f>>4, comp=f&15
    float4 rk0, rk1, rv0, rv1;

    // prologue: stage tile 0
    {
        size_t tb = gbase;
        rk0 = kb4[tb + (size_t)(f0>>4)*64 + (f0&15)];
        rk1 = kb4[tb + (size_t)(f1>>4)*64 + (f1&15)];
        rv0 = vb4[tb + (size_t)(f0>>4)*64 + (f0&15)];
        rv1 = vb4[tb + (size_t)(f1>>4)*64 + (f1&15)];
        kt[0][f0>>4][f0&15] = rk0;  kt[0][f1>>4][f1&15] = rk1;
        vt[0][f0>>4][f0&15] = rv0;  vt[0][f1>>4][f1&15] = rv1;
    }
    __syncthreads();

    const int NT = CHUNK / TK;   // 4
    for (int tile = 0; tile < NT; tile++) {
        int cur = tile & 1;
        if (tile + 1 < NT) {     // issue next tile's loads (hide under compute)
            size_t tb = gbase + (size_t)(tile+1)*TK*64;
            rk0 = kb4[tb + (size_t)(f0>>4)*64 + (f0&15)];
            rk1 = kb4[tb + (size_t)(f1>>4)*64 + (f1&15)];
            rv0 = vb4[tb + (size_t)(f0>>4)*64 + (f0&15)];
            rv1 = vb4[tb + (size_t)(f1>>4)*64 + (f1&15)];
        }
#pragma unroll 4
        for (int j = 0; j < TK; j++) {
            float d0 = 0.f, d1 = 0.f, d2 = 0.f, d3 = 0.f;
#pragma unroll
            for (int i = 0; i < 16; i += 4) {
                float4 k0 = kt[cur][j][i+0];
                float4 k1 = kt[cur][j][i+1];
                float4 k2 = kt[cur][j][i+2];
                float4 k3 = kt[cur][j][i+3];
                d0 += q[i+0].x*k0.x + q[i+0].y*k0.y + q[i+0].z*k0.z + q[i+0].w*k0.w;
                d1 += q[i+1].x*k1.x + q[i+1].y*k1.y + q[i+1].z*k1.z + q[i+1].w*k1.w;
                d2 += q[i+2].x*k2.x + q[i+2].y*k2.y + q[i+2].z*k2.z + q[i+2].w*k2.w;
                d3 += q[i+3].x*k3.x + q[i+3].y*k3.y + q[i+3].z*k3.z + q[i+3].w*k3.w;
            }
            float p = ((d0 + d1) + (d2 + d3)) * 0.125f;   // 1/sqrt(64)
            float mn = fmaxf(mr, p);
            float sc = __expf(mr - mn);
            float e  = __expf(p - mn);
            lr = lr*sc + e;
#pragma unroll
            for (int i = 0; i < 16; i++) {
                float4 vv = vt[cur][j][i];
                a[i].x = a[i].x*sc + e*vv.x;
                a[i].y = a[i].y*sc + e*vv.y;
                a[i].z = a[i].z*sc + e*vv.z;
                a[i].w = a[i].w*sc + e*vv.w;
            }
            mr = mn;
        }
        if (tile + 1 < NT) {
            __syncthreads();                       // all waves done reading cur-1 state
            int nb = (tile + 1) & 1;
            kt[nb][f0>>4][f0&15] = rk0;  kt[nb][f1>>4][f1&15] = rk1;
            vt[nb][f0>>4][f0&15] = rv0;  vt[nb][f1>>4][f1&15] = rv1;
            __syncthreads();                       // writes visible before next compute
        }
    }
    int pi = (chunk*4 + h)*NCRS + row;
    pm[pi] = mr; pl[pi] = lr;
    float4* po = (float4*)(pacc + (size_t)pi*64);
#pragma unroll
    for (int i = 0; i < 16; i++) po[i] = a[i];
}

__global__ __launch_bounds__(256) void attn_combine(
    const float* __restrict__ pm, const float* __restrict__ pl,
    const float* __restrict__ pacc, float* __restrict__ msg)
{
    int row = blockIdx.x, t = threadIdx.x;
    int h = t >> 6, d = t & 63;
    float m = -INFINITY;
#pragma unroll
    for (int c = 0; c < NCHUNK; c++) m = fmaxf(m, pm[(c*4 + h)*NCRS + row]);
    float lsum = 0.f, asum = 0.f;
#pragma unroll
    for (int c = 0; c < NCHUNK; c++) {
        int pi = (c*4 + h)*NCRS + row;
        float w = __expf(pm[pi] - m);
        lsum += pl[pi] * w;
        asum += pacc[(size_t)pi*64 + d] * w;
    }
    msg[(size_t)row*GD + h*64 + d] = asum / lsum;
}

// out = x + [x, msg] @ Wm + bm, row-tiled
__global__ __launch_bounds__(256) void cross_combine(
    const float* __restrict__ x, const float* __restrict__ msg,
    const float* __restrict__ Wm, const float* __restrict__ bm,
    float* __restrict__ out)
{
    int t = threadIdx.x, n0 = blockIdx.x * LROWS;
    __shared__ float xs[GD][LROWS], ms[GD][LROWS];
    for (int i = t; i < LROWS*GD; i += 256) {
        int r = i >> 8, c = i & 255;
        xs[c][r] = x[(size_t)(n0+r)*GD + c];
        ms[c][r] = msg[(size_t)(n0+r)*GD + c];
    }
    __syncthreads();
    float a[LROWS];
#pragma unroll
    for (int r = 0; r < LROWS; r++) a[r] = bm[t];
    for (int c = 0; c < GD; c++) {
        float w1 = Wm[c*GD + t];
        float w2 = Wm[(GD + c)*GD + t];
        float4 x0 = *(const float4*)&xs[c][0];
        float4 x1 = *(const float4*)&xs[c][4];
        float4 m0 = *(const float4*)&ms[c][0];
        float4 m1 = *(const float4*)&ms[c][4];
        a[0] += x0.x*w1 + m0.x*w2; a[1] += x0.y*w1 + m0.y*w2;
        a[2] += x0.z*w1 + m0.z*w2; a[3] += x0.w*w1 + m0.w*w2;
        a[4] += x1.x*w1 + m1.x*w2; a[5] += x1.y*w1 + m1.y*w2;
        a[6] += x1.z*w1 + m1.z*w2; a[7] += x1.w*w1 + m1.w*w2;
    }
#pragma unroll
    for (int r = 0; r < LROWS; r++)
        out[(size_t)(n0+r)*GD + t] = xs[t][r] + a[r];
}

// =====================================================================
// proj + l2norm + score
// =====================================================================
__global__ __launch_bounds__(256) void proj_fused(
    const float* __restrict__ g3, const float* __restrict__ Wp,
    const float* __restrict__ bp, const float* __restrict__ Wsc,
    const float* __restrict__ bsc, float* __restrict__ feats,
    float* __restrict__ fnorm, float* __restrict__ scores)
{
    int n = blockIdx.x, t = threadIdx.x;
    __shared__ float xi[GD];
    __shared__ float red[256];
    xi[t] = g3[(size_t)n*GD + t];
    __syncthreads();
    float acc = bp[t];
    for (int c = 0; c < GD; c++) acc += xi[c] * Wp[c*GD + t];
    feats[(size_t)n*GD + t] = acc;
    red[t] = acc * acc; __syncthreads();
    for (int s = 128; s > 0; s >>= 1) { if (t < s) red[t] += red[t+s]; __syncthreads(); }
    float nrm = fmaxf(sqrtf(red[0]), 1e-12f);
    __syncthreads();
    fnorm[(size_t)n*GD + t] = acc / nrm;
    red[t] = acc * Wsc[t]; __syncthreads();
    for (int s = 128; s > 0; s >>= 1) { if (t < s) red[t] += red[t+s]; __syncthreads(); }
    if (t == 0) scores[n] = red[0] + bsc[0];
}

// ip, 4 rows per block
__global__ __launch_bounds__(256) void ip_kernel(
    const float* __restrict__ fnorm, float* __restrict__ ip)
{
    int t = threadIdx.x, n0 = blockIdx.x * 4;
    __shared__ float xs[GD][4];
    for (int i = t; i < 4*GD; i += 256) {
        int r = i >> 8, c = i & 255;
        xs[c][r] = fnorm[(size_t)(n0+r)*GD + c];
    }
    __syncthreads();
    const float4* ft = (const float4*)(fnorm + (size_t)NSRC*GD);
    for (int m = t; m < NSRC; m += 256) {
        const float4* fr = ft + (size_t)m*(GD/4);
        float a0 = 0.f, a1 = 0.f, a2 = 0.f, a3 = 0.f;
        for (int c4 = 0; c4 < GD/4; c4++) {
            float4 f = fr[c4];
            float4 xa = *(const float4*)&xs[c4*4+0][0];
            float4 xb = *(const float4*)&xs[c4*4+1][0];
            float4 xc = *(const float4*)&xs[c4*4+2][0];
            float4 xd = *(const float4*)&xs[c4*4+3][0];
            a0 += f.x*xa.x + f.y*xb.x + f.z*xc.x + f.w*xd.x;
            a1 += f.x*xa.y + f.y*xb.y + f.z*xc.y + f.w*xd.y;
            a2 += f.x*xa.z + f.y*xb.z + f.z*xc.z + f.w*xd.z;
            a3 += f.x*xa.w + f.y*xb.w + f.z*xc.w + f.w*xd.w;
        }
        ip[(size_t)(n0+0)*NSRC + m] = a0;
        ip[(size_t)(n0+1)*NSRC + m] = a1;
        ip[(size_t)(n0+2)*NSRC + m] = a2;
        ip[(size_t)(n0+3)*NSRC + m] = a3;
    }
}

// saliency
template<bool COL>
__global__ __launch_bounds__(256) void saliency_kernel(
    const float* __restrict__ ip, const float* __restrict__ scores_other,
    const float* __restrict__ epsv, float* __restrict__ sal_out)
{
    int n = blockIdx.x, t = threadIdx.x;
    float T = expf(epsv[0]) + 0.03f;
    __shared__ float red[256];
    float vals[4];
    float m = -INFINITY;
#pragma unroll
    for (int ii = 0; ii < 4; ii++) {
        int i = t + ii*256;
        float vv = COL ? ip[(size_t)i*NSRC + n] : ip[(size_t)n*NSRC + i];
        vv /= T;
        vals[ii] = vv;
        m = fmaxf(m, vv);
    }
    red[t] = m; __syncthreads();
    for (int s = 128; s > 0; s >>= 1) { if (t < s) red[t] = fmaxf(red[t], red[t+s]); __syncthreads(); }
    float mx = red[0]; __syncthreads();
    float se = 0.f, wsum = 0.f;
#pragma unroll
    for (int ii = 0; ii < 4; ii++) {
        int i = t + ii*256;
        float e = expf(vals[ii] - mx);
        se += e; wsum += e * scores_other[i];
    }
    red[t] = se; __syncthreads();
    for (int s = 128; s > 0; s >>= 1) { if (t < s) red[t] += red[t+s]; __syncthreads(); }
    float S = red[0]; __syncthreads();
    red[t] = wsum; __syncthreads();
    for (int s = 128; s > 0; s >>= 1) { if (t < s) red[t] += red[t+s]; __syncthreads(); }
    if (t == 0) sal_out[n] = red[0] / S;
}

// =====================================================================
// decoder — thread per row, W via wave-uniform loads, acc in registers.
// =====================================================================
__global__ __launch_bounds__(256) void decoder_kernel(
    const float* __restrict__ feats, const float* __restrict__ scores,
    const float* __restrict__ sal, const float* __restrict__ skip,
    const int* __restrict__ ups, const float* __restrict__ Wd,
    const float* __restrict__ bd, float* __restrict__ outf,
    float* __restrict__ outso, float* __restrict__ outss)
{
    int row = blockIdx.x * 256 + threadIdx.x;
    if (row >= NFINE) return;
    int u = ups[row];
    float acc[DECOUT];
#pragma unroll
    for (int j = 0; j < DECOUT; j++) acc[j] = bd[j];
    float x0 = scores[u], x1 = sal[u];
#pragma unroll
    for (int j = 0; j < DECOUT; j++) acc[j] += x0 * Wd[j];
#pragma unroll
    for (int j = 0; j < DECOUT; j++) acc[j] += x1 * Wd[DECOUT + j];
    const float4* fr = (const float4*)(feats + (size_t)u * GD);
    for (int c4 = 0; c4 < GD/4; c4++) {
        float4 xv = fr[c4];
        const float* wr = Wd + (size_t)(2 + c4*4) * DECOUT;
#pragma unroll
        for (int j = 0; j < DECOUT; j++) acc[j] += xv.x * wr[j];
#pragma unroll
        for (int j = 0; j < DECOUT; j++) acc[j] += xv.y * wr[DECOUT + j];
#pragma unroll
        for (int j = 0; j < DECOUT; j++) acc[j] += xv.z * wr[2*DECOUT + j];
#pragma unroll
        for (int j = 0; j < DECOUT; j++) acc[j] += xv.w * wr[3*DECOUT + j];
    }
    const float4* sr = (const float4*)(skip + (size_t)row * C1D);
    for (int c4 = 0; c4 < C1D/4; c4++) {
        float4 xv = sr[c4];
        const float* wr = Wd + (size_t)(2 + GD + c4*4) * DECOUT;
#pragma unroll
        for (int j = 0; j < DECOUT; j++) acc[j] += xv.x * wr[j];
#pragma unroll
        for (int j = 0; j < DECOUT; j++) acc[j] += xv.y * wr[DECOUT + j];
#pragma unroll
        for (int j = 0; j < DECOUT; j++) acc[j] += xv.z * wr[2*DECOUT + j];
#pragma unroll
        for (int j = 0; j < DECOUT; j++) acc[j] += xv.w * wr[3*DECOUT + j];
    }
    float sq = 0.f;
#pragma unroll
    for (int j = 0; j < FINALD; j++) sq += acc[j]*acc[j];
    float inv = 1.f / fmaxf(sqrtf(sq), 1e-12f);
    float4* op = (float4*)(outf + (size_t)row * FINALD);
#pragma unroll
    for (int i = 0; i < 8; i++)
        op[i] = make_float4(acc[4*i]*inv, acc[4*i+1]*inv, acc[4*i+2]*inv, acc[4*i+3]*inv);
    float so = 1.f/(1.f + __expf(-acc[32]));
    so = fminf(fmaxf(so, 0.f), 1.f); if (!(so == so)) so = 0.f;
    float ss = 1.f/(1.f + __expf(-acc[33]));
    ss = fminf(fmaxf(ss, 0.f), 1.f); if (!(ss == ss)) ss = 0.f;
    outso[row] = so; outss[row] = ss;
}

// =====================================================================
extern "C" void kernel_launch(void* const* d_in, const int* in_sizes, int n_in,
                              void* d_out, int out_size, void* d_ws, size_t ws_size,
                              hipStream_t stream)
{
    const float* points_f     = (const float*)d_in[0];
    const float* points_c     = (const float*)d_in[1];
    const float* features     = (const float*)d_in[2];
    const float* kp_f         = (const float*)d_in[3];
    const float* kp_c         = (const float*)d_in[4];
    const float* W_kp1        = (const float*)d_in[5];
    const float* W_kp2        = (const float*)d_in[6];
    const float* W_bottle     = (const float*)d_in[7];
    const float* b_bottle     = (const float*)d_in[8];
    const float* W_self1      = (const float*)d_in[9];
    const float* b_self1      = (const float*)d_in[10];
    const float* Wq           = (const float*)d_in[11];
    const float* Wk           = (const float*)d_in[12];
    const float* Wv           = (const float*)d_in[13];
    const float* W_cross      = (const float*)d_in[14];
    const float* b_cross      = (const float*)d_in[15];
    const float* W_self2      = (const float*)d_in[16];
    const float* b_self2      = (const float*)d_in[17];
    const float* W_proj       = (const float*)d_in[18];
    const float* b_proj       = (const float*)d_in[19];
    const float* W_score      = (const float*)d_in[20];
    const float* b_score      = (const float*)d_in[21];
    const float* epsilon      = (const float*)d_in[22];
    const float* W_dec        = (const float*)d_in[23];
    const float* b_dec        = (const float*)d_in[24];
    const int*   neighbors_f  = (const int*)d_in[25];
    const int*   pool_idx     = (const int*)d_in[26];
    const int*   upsample_idx = (const int*)d_in[27];

    float* ws = (float*)d_ws;
    size_t o = 0;
    auto alloc = [&](size_t nfl) { float* p = ws + o; o += (nfl + 63) & ~(size_t)63; return p; };
    float* x_f    = alloc((size_t)NFINE * C1D);
    float* g1     = alloc((size_t)NCRS * GD);
    float* qb     = alloc((size_t)NCRS * GD);
    float* kb     = alloc((size_t)NCRS * GD);
    float* vb     = alloc((size_t)NCRS * GD);
    float* msg    = alloc((size_t)NCRS * GD);
    float* scores = alloc(NCRS);
    float* sal    = alloc(NCRS);
    int*   knn_b  = (int*)alloc(NCRS * DGK);
    // union: layout A (pipeline tensors) / layout B (attn partials).
    // A tensors are all dead during [attn_flash, attn_combine).
    size_t uA = (size_t)NCRS*C2D + (size_t)NCRS*GD*5 + (size_t)NSRC*NSRC;
    size_t uB = (size_t)2*NCRS*4*NCHUNK + (size_t)NCRS*4*NCHUNK*64;
    float* ub = alloc(uA > uB ? uA : uB);
    float* x_c     = ub;
    float* feats_c = x_c + (size_t)NCRS*C2D;
    float* g2      = feats_c + (size_t)NCRS*GD;
    float* g3      = g2 + (size_t)NCRS*GD;
    float* feats   = g3 + (size_t)NCRS*GD;
    float* fnorm   = feats + (size_t)NCRS*GD;
    float* ip      = fnorm + (size_t)NCRS*GD;
    float* pm      = ub;
    float* pl      = pm + (size_t)NCRS*4*NCHUNK;
    float* pacc    = pl + (size_t)NCRS*4*NCHUNK;

    float* outf  = (float*)d_out;
    float* outso = outf + (size_t)NFINE * FINALD;
    float* outss = outso + NFINE;

    // encoder
    kpconv_fine<<<NFINE/4, 256, 0, stream>>>(points_f, features, neighbors_f, kp_f, W_kp1, x_f);
    kpconv_coarse<<<NCRS/CTILE, 256, 0, stream>>>(points_c, points_f, x_f, pool_idx, kp_c, W_kp2, x_c);
    linear_rows<C2D, GD, true><<<NCRS/LROWS, GD, 0, stream>>>(x_c, W_bottle, b_bottle, feats_c);

    // GNN
    knn_kernel<<<NCRS, 256, 0, stream>>>(points_c, knn_b);
    self_layer_kernel<<<NSRC/SROWS, 256, 0, stream>>>(feats_c, knn_b, W_self1, b_self1, g1);
    self_layer_kernel<<<NSRC/SROWS, 256, 0, stream>>>(feats_c + (size_t)NSRC*GD, knn_b + NSRC*DGK,
                                                      W_self1, b_self1, g1 + (size_t)NSRC*GD);
    qkv_kernel<<<NCRS/LROWS, 256, 0, stream>>>(g1, Wq, Wk, Wv, qb, kb, vb);
    attn_flash<<<256, 256, 0, stream>>>(qb, kb, vb, pm, pl, pacc);
    attn_combine<<<NCRS, 256, 0, stream>>>(pm, pl, pacc, msg);
    cross_combine<<<NCRS/LROWS, 256, 0, stream>>>(g1, msg, W_cross, b_cross, g2);
    self_layer_kernel<<<NSRC/SROWS, 256, 0, stream>>>(g2, knn_b, W_self2, b_self2, g3);
    self_layer_kernel<<<NSRC/SROWS, 256, 0, stream>>>(g2 + (size_t)NSRC*GD, knn_b + NSRC*DGK,
                                                      W_self2, b_self2, g3 + (size_t)NSRC*GD);

    // head
    proj_fused<<<NCRS, 256, 0, stream>>>(g3, W_proj, b_proj, W_score, b_score, feats, fnorm, scores);
    ip_kernel<<<NSRC/4, 256, 0, stream>>>(fnorm, ip);
    saliency_kernel<false><<<NSRC, 256, 0, stream>>>(ip, scores + NSRC, epsilon, sal);
    saliency_kernel<true><<<NSRC, 256, 0, stream>>>(ip, scores, epsilon, sal + NSRC);

    // decoder
    decoder_kernel<<<(NFINE + 255)/256, 256, 0, stream>>>(feats, scores, sal, x_f, upsample_idx,
                                                          W_dec, b_dec, outf, outso, outss);
}

// Round 5
// 544.749 us; speedup vs baseline: 3.4106x; 1.3972x over previous
//
#include <hip/hip_runtime.h>
#include <math.h>

// ---- problem constants ----
#define NFINE   80000
#define NCRS    2048
#define NSRC    1024
#define NNB     30
#define KP      15
#define C1D     128
#define C2D     256
#define GD      256
#define DGK     10
#define FINALD  32
#define DECIN   386
#define DECOUT  34

#define NCHUNK  8      // attention key-split
#define CHUNK   128    // 1024 / NCHUNK
#define TK      32     // attention LDS key tile

// =====================================================================
// Stage 1: kpconv fine — one wave per point, 4 points per block.
// contrib padded to 17 floats: stride coprime with 32 banks.
// =====================================================================
__global__ __launch_bounds__(256) void kpconv_fine(
    const float* __restrict__ pts, const float* __restrict__ feat,
    const int* __restrict__ nbr, const float* __restrict__ kp,
    const float* __restrict__ W, float* __restrict__ out)
{
    int t = threadIdx.x, w = t >> 6, lane = t & 63;
    int n = blockIdx.x * 4 + w;
    __shared__ float contrib[4][NNB][17];
    __shared__ float h[4][KP + 1];
    float kx[KP], ky[KP], kz[KP], kk[KP];
#pragma unroll
    for (int k = 0; k < KP; k++) {
        kx[k] = kp[k*3]; ky[k] = kp[k*3+1]; kz[k] = kp[k*3+2];
        kk[k] = kx[k]*kx[k] + ky[k]*ky[k] + kz[k]*kz[k];
    }
    if (lane < NNB) {
        float qx = pts[n*3], qy = pts[n*3+1], qz = pts[n*3+2];
        int id = nbr[n*NNB + lane];
        float rx = pts[id*3]-qx, ry = pts[id*3+1]-qy, rz = pts[id*3+2]-qz;
        float rr = rx*rx + ry*ry + rz*rz;
        float f = feat[id];
#pragma unroll
        for (int k = 0; k < KP; k++) {
            float d2 = rr + kk[k] - 2.f*(rx*kx[k] + ry*ky[k] + rz*kz[k]);
            float infl = fmaxf(1.f - sqrtf(fmaxf(d2, 1e-12f)), 0.f); // extent=1
            contrib[w][lane][k] = infl * f;
        }
    }
    __syncthreads();
    if (lane < KP) {
        float s = 0.f;
#pragma unroll
        for (int j = 0; j < NNB; j++) s += contrib[w][j][lane];
        h[w][lane] = s;
    }
    __syncthreads();
    float a0 = 0.f, a1 = 0.f;
#pragma unroll
    for (int k = 0; k < KP; k++) {
        float hk = h[w][k];
        a0 += hk * W[k*C1D + lane];
        a1 += hk * W[k*C1D + 64 + lane];
    }
    out[(size_t)n*C1D + lane]      = a0;
    out[(size_t)n*C1D + 64 + lane] = a1;
}

// =====================================================================
// Stage 2a: hh for each coarse point -> global (2048 blocks, high TLP)
// =====================================================================
__global__ __launch_bounds__(256) void hh_kernel(
    const float* __restrict__ pc, const float* __restrict__ pf,
    const float* __restrict__ xf, const int* __restrict__ pool,
    const float* __restrict__ kp, float* __restrict__ hhg)
{
    int n = blockIdx.x, t = threadIdx.x;
    __shared__ float kx[KP], ky[KP], kz[KP], kk[KP];
    __shared__ float rel[NNB][4];
    __shared__ int   ids[NNB];
    __shared__ float infl[NNB][KP + 1];
    __shared__ float nf[NNB][C1D];
    if (t < KP) {
        float a = kp[t*3], b = kp[t*3+1], c = kp[t*3+2];
        kx[t] = a; ky[t] = b; kz[t] = c; kk[t] = a*a + b*b + c*c;
    }
    if (t < NNB) {
        int id = pool[n*NNB + t]; ids[t] = id;
        float qx = pc[n*3], qy = pc[n*3+1], qz = pc[n*3+2];
        float rx = pf[id*3]-qx, ry = pf[id*3+1]-qy, rz = pf[id*3+2]-qz;
        rel[t][0] = rx; rel[t][1] = ry; rel[t][2] = rz;
        rel[t][3] = rx*rx + ry*ry + rz*rz;
    }
    __syncthreads();
    for (int i = t; i < NNB*KP; i += 256) {
        int j = i / KP, kq = i % KP;
        float d2 = rel[j][3] + kk[kq]
                 - 2.f*(rel[j][0]*kx[kq] + rel[j][1]*ky[kq] + rel[j][2]*kz[kq]);
        infl[j][kq] = fmaxf(1.f - sqrtf(fmaxf(d2, 1e-12f)) * 0.5f, 0.f); // extent=2
    }
    for (int i = t; i < NNB*C1D; i += 256) {
        int j = i >> 7, c = i & 127;
        nf[j][c] = xf[(size_t)ids[j]*C1D + c];
    }
    __syncthreads();
    for (int i = t; i < KP*C1D; i += 256) {
        int kq = i >> 7, c = i & 127;
        float s = 0.f;
#pragma unroll
        for (int j = 0; j < NNB; j++) s += infl[j][kq] * nf[j][c];
        hhg[(size_t)n*(KP*C1D) + i] = s;
    }
}

// =====================================================================
// Generic row-tiled linear: TR rows/block, COUT threads.
// Used for: x_c = hh @ W_kp2 (K=1920), bottleneck (K=256).
// =====================================================================
template<int CIN, int COUT, int TR, bool BIAS>
__global__ __launch_bounds__(COUT) void linear_rows(
    const float* __restrict__ in, const float* __restrict__ W,
    const float* __restrict__ b, float* __restrict__ out)
{
    int t = threadIdx.x, n0 = blockIdx.x * TR;
    __shared__ float xi[CIN][TR];
    for (int i = t; i < TR*CIN; i += COUT) {
        int r = i / CIN, c = i % CIN;
        xi[c][r] = in[(size_t)(n0+r)*CIN + c];
    }
    __syncthreads();
    float a[TR];
#pragma unroll
    for (int r = 0; r < TR; r++) a[r] = BIAS ? b[t] : 0.f;
    for (int c = 0; c < CIN; c++) {
        float wv = W[(size_t)c*COUT + t];
        float4 x0 = *(const float4*)&xi[c][0];
        a[0] += x0.x*wv; a[1] += x0.y*wv; a[2] += x0.z*wv; a[3] += x0.w*wv;
    }
#pragma unroll
    for (int r = 0; r < TR; r++) out[(size_t)(n0+r)*COUT + t] = a[r];
}

// =====================================================================
// self-layer GEMM: Y[n][0:256] = X[n]@W[0:256,:], Y[n][256:512] = X[n]@W[256:512,:]
// 512 threads (one per output col), 4 rows per block.
// =====================================================================
__global__ __launch_bounds__(512) void self_gemm(
    const float* __restrict__ x, const float* __restrict__ W,
    float* __restrict__ Y)
{
    int t = threadIdx.x, n0 = blockIdx.x * 4;
    __shared__ float xi[GD][4];
    for (int i = t; i < 4*GD; i += 512) {
        int r = i >> 8, c = i & 255;
        xi[c][r] = x[(size_t)(n0+r)*GD + c];
    }
    __syncthreads();
    const float* wcol = (t < GD) ? (W + t) : (W + (size_t)GD*GD + (t - GD));
    float a0 = 0.f, a1 = 0.f, a2 = 0.f, a3 = 0.f;
    for (int c = 0; c < GD; c++) {
        float wv = wcol[(size_t)c*GD];
        float4 xv = *(const float4*)&xi[c][0];
        a0 += xv.x*wv; a1 += xv.y*wv; a2 += xv.z*wv; a3 += xv.w*wv;
    }
    Y[(size_t)(n0+0)*512 + t] = a0;
    Y[(size_t)(n0+1)*512 + t] = a1;
    Y[(size_t)(n0+2)*512 + t] = a2;
    Y[(size_t)(n0+3)*512 + t] = a3;
}

// edge conv max: out[n][t] = max_j relu(A[n][t] - B[n][t] + B[idx_j][t] + b[t])
__global__ __launch_bounds__(256) void edge_max(
    const float* __restrict__ Y, const int* __restrict__ knn,
    const float* __restrict__ b, float* __restrict__ out)
{
    int n = blockIdx.x, t = threadIdx.x;
    int base = (n < NSRC) ? 0 : NSRC;
    __shared__ int ids[DGK];
    if (t < DGK) ids[t] = base + knn[n*DGK + t];
    __syncthreads();
    float a  = Y[(size_t)n*512 + t];
    float bn = Y[(size_t)n*512 + GD + t];
    float cst = a - bn + b[t];
    float acc = 0.f;
#pragma unroll
    for (int j = 0; j < DGK; j++) {
        float bj = Y[(size_t)ids[j]*512 + GD + t];
        acc = fmaxf(acc, fmaxf(cst + bj, 0.f));
    }
    out[(size_t)n*GD + t] = acc;
}

// fused q,k,v projections, 4 rows per block
__global__ __launch_bounds__(256) void qkv_kernel(
    const float* __restrict__ x, const float* __restrict__ Wq,
    const float* __restrict__ Wk, const float* __restrict__ Wv,
    float* __restrict__ qb, float* __restrict__ kb, float* __restrict__ vb)
{
    int t = threadIdx.x, n0 = blockIdx.x * 4;
    __shared__ float xi[GD][4];
    for (int i = t; i < 4*GD; i += 256) {
        int r = i >> 8, c = i & 255;
        xi[c][r] = x[(size_t)(n0+r)*GD + c];
    }
    __syncthreads();
    const float* Ws[3] = {Wq, Wk, Wv};
    float* outs[3] = {qb, kb, vb};
#pragma unroll
    for (int m = 0; m < 3; m++) {
        const float* W = Ws[m];
        float a0 = 0.f, a1 = 0.f, a2 = 0.f, a3 = 0.f;
        for (int c = 0; c < GD; c++) {
            float wv = W[c*GD + t];
            float4 xv = *(const float4*)&xi[c][0];
            a0 += xv.x*wv; a1 += xv.y*wv; a2 += xv.z*wv; a3 += xv.w*wv;
        }
        float* o = outs[m];
        o[(size_t)(n0+0)*GD + t] = a0;
        o[(size_t)(n0+1)*GD + t] = a1;
        o[(size_t)(n0+2)*GD + t] = a2;
        o[(size_t)(n0+3)*GD + t] = a3;
    }
}

// =====================================================================
// knn — block per query, LDS d2 + 10 deterministic min-selections.
// =====================================================================
__global__ __launch_bounds__(256) void knn_kernel(
    const float* __restrict__ pts, int* __restrict__ knn)
{
    int g = blockIdx.x;            // query 0..2047
    int t = threadIdx.x;
    int base = (g < NSRC) ? 0 : NSRC;
    int local = g - base;
    const float* P = pts + (size_t)base*3;
    __shared__ float d2s[NSRC];
    __shared__ float wval[4];
    __shared__ int   widx[4];
    float qx = P[local*3], qy = P[local*3+1], qz = P[local*3+2];
    float sqn = qx*qx + qy*qy + qz*qz;
#pragma unroll
    for (int ii = 0; ii < 4; ii++) {
        int m = t + ii*256;
        float px = P[m*3], py = P[m*3+1], pz = P[m*3+2];
        float sqm = px*px + py*py + pz*pz;
        d2s[m] = sqn + sqm - 2.f*(qx*px + qy*py + qz*pz);
    }
    __syncthreads();
    for (int r = 0; r < DGK; r++) {
        float bv = 3.4e38f; int bidx = NSRC;
#pragma unroll
        for (int ii = 0; ii < 4; ii++) {
            int m = t + ii*256;
            float v = d2s[m];
            if (v < bv) { bv = v; bidx = m; }   // ascending m: ties keep lower
        }
#pragma unroll
        for (int off = 32; off >= 1; off >>= 1) {
            float ov = __shfl_xor(bv, off);
            int   oi = __shfl_xor(bidx, off);
            if (ov < bv || (ov == bv && oi < bidx)) { bv = ov; bidx = oi; }
        }
        if ((t & 63) == 0) { wval[t >> 6] = bv; widx[t >> 6] = bidx; }
        __syncthreads();
        if (t == 0) {
            float fv = wval[0]; int fi = widx[0];
#pragma unroll
            for (int wv2 = 1; wv2 < 4; wv2++)
                if (wval[wv2] < fv || (wval[wv2] == fv && widx[wv2] < fi)) {
                    fv = wval[wv2]; fi = widx[wv2];
                }
            knn[g*DGK + r] = fi;
            d2s[fi] = 3.4e38f;
        }
        __syncthreads();
    }
}

// =====================================================================
// attention: block-level flash with double-buffered LDS K/V staging.
// =====================================================================
__global__ __launch_bounds__(256) void attn_flash(
    const float* __restrict__ qb, const float* __restrict__ kb,
    const float* __restrict__ vb, float* __restrict__ pm,
    float* __restrict__ pl, float* __restrict__ pacc)
{
    int bidx = blockIdx.x;
    int h = bidx & 3, chunk = (bidx >> 2) & 7, rb = bidx >> 5;
    int t = threadIdx.x;
    int row = rb * 256 + t;
    int kbase = (row < NSRC) ? NSRC : 0;   // uniform across block

    __shared__ float4 kt[2][TK][16];
    __shared__ float4 vt[2][TK][16];

    const float4* kb4 = (const float4*)kb;
    const float4* vb4 = (const float4*)vb;
    size_t gbase = ((size_t)(kbase + chunk*CHUNK)) * 64 + h*16;

    float4 q[16];
    const float4* q4 = (const float4*)(qb + (size_t)row*GD + h*64);
#pragma unroll
    for (int i = 0; i < 16; i++) q[i] = q4[i];
    float4 a[16];
#pragma unroll
    for (int i = 0; i < 16; i++) a[i] = make_float4(0.f, 0.f, 0.f, 0.f);
    float mr = -INFINITY, lr = 0.f;

    int f0 = t, f1 = t + 256;             // flat float4 index: key=f>>4, comp=f&15
    float4 rk0, rk1, rv0, rv1;

    {
        size_t tb = gbase;
        rk0 = kb4[tb + (size_t)(f0>>4)*64 + (f0&15)];
        rk1 = kb4[tb + (size_t)(f1>>4)*64 + (f1&15)];
        rv0 = vb4[tb + (size_t)(f0>>4)*64 + (f0&15)];
        rv1 = vb4[tb + (size_t)(f1>>4)*64 + (f1&15)];
        kt[0][f0>>4][f0&15] = rk0;  kt[0][f1>>4][f1&15] = rk1;
        vt[0][f0>>4][f0&15] = rv0;  vt[0][f1>>4][f1&15] = rv1;
    }
    __syncthreads();

    const int NT = CHUNK / TK;   // 4
    for (int tile = 0; tile < NT; tile++) {
        int cur = tile & 1;
        if (tile + 1 < NT) {
            size_t tb = gbase + (size_t)(tile+1)*TK*64;
            rk0 = kb4[tb + (size_t)(f0>>4)*64 + (f0&15)];
            rk1 = kb4[tb + (size_t)(f1>>4)*64 + (f1&15)];
            rv0 = vb4[tb + (size_t)(f0>>4)*64 + (f0&15)];
            rv1 = vb4[tb + (size_t)(f1>>4)*64 + (f1&15)];
        }
#pragma unroll 4
        for (int j = 0; j < TK; j++) {
            float d0 = 0.f, d1 = 0.f, d2 = 0.f, d3 = 0.f;
#pragma unroll
            for (int i = 0; i < 16; i += 4) {
                float4 k0 = kt[cur][j][i+0];
                float4 k1 = kt[cur][j][i+1];
                float4 k2 = kt[cur][j][i+2];
                float4 k3 = kt[cur][j][i+3];
                d0 += q[i+0].x*k0.x + q[i+0].y*k0.y + q[i+0].z*k0.z + q[i+0].w*k0.w;
                d1 += q[i+1].x*k1.x + q[i+1].y*k1.y + q[i+1].z*k1.z + q[i+1].w*k1.w;
                d2 += q[i+2].x*k2.x + q[i+2].y*k2.y + q[i+2].z*k2.z + q[i+2].w*k2.w;
                d3 += q[i+3].x*k3.x + q[i+3].y*k3.y + q[i+3].z*k3.z + q[i+3].w*k3.w;
            }
            float p = ((d0 + d1) + (d2 + d3)) * 0.125f;   // 1/sqrt(64)
            float mn = fmaxf(mr, p);
            float sc = __expf(mr - mn);
            float e  = __expf(p - mn);
            lr = lr*sc + e;
#pragma unroll
            for (int i = 0; i < 16; i++) {
                float4 vv = vt[cur][j][i];
                a[i].x = a[i].x*sc + e*vv.x;
                a[i].y = a[i].y*sc + e*vv.y;
                a[i].z = a[i].z*sc + e*vv.z;
                a[i].w = a[i].w*sc + e*vv.w;
            }
            mr = mn;
        }
        if (tile + 1 < NT) {
            __syncthreads();
            int nb = (tile + 1) & 1;
            kt[nb][f0>>4][f0&15] = rk0;  kt[nb][f1>>4][f1&15] = rk1;
            vt[nb][f0>>4][f0&15] = rv0;  vt[nb][f1>>4][f1&15] = rv1;
            __syncthreads();
        }
    }
    int pi = (chunk*4 + h)*NCRS + row;
    pm[pi] = mr; pl[pi] = lr;
    float4* po = (float4*)(pacc + (size_t)pi*64);
#pragma unroll
    for (int i = 0; i < 16; i++) po[i] = a[i];
}

__global__ __launch_bounds__(256) void attn_combine(
    const float* __restrict__ pm, const float* __restrict__ pl,
    const float* __restrict__ pacc, float* __restrict__ msg)
{
    int row = blockIdx.x, t = threadIdx.x;
    int h = t >> 6, d = t & 63;
    float m = -INFINITY;
#pragma unroll
    for (int c = 0; c < NCHUNK; c++) m = fmaxf(m, pm[(c*4 + h)*NCRS + row]);
    float lsum = 0.f, asum = 0.f;
#pragma unroll
    for (int c = 0; c < NCHUNK; c++) {
        int pi = (c*4 + h)*NCRS + row;
        float w = __expf(pm[pi] - m);
        lsum += pl[pi] * w;
        asum += pacc[(size_t)pi*64 + d] * w;
    }
    msg[(size_t)row*GD + h*64 + d] = asum / lsum;
}

// out = x + [x, msg] @ Wm + bm, 4 rows/block
__global__ __launch_bounds__(256) void cross_combine(
    const float* __restrict__ x, const float* __restrict__ msg,
    const float* __restrict__ Wm, const float* __restrict__ bm,
    float* __restrict__ out)
{
    int t = threadIdx.x, n0 = blockIdx.x * 4;
    __shared__ float xs[GD][4], ms[GD][4];
    for (int i = t; i < 4*GD; i += 256) {
        int r = i >> 8, c = i & 255;
        xs[c][r] = x[(size_t)(n0+r)*GD + c];
        ms[c][r] = msg[(size_t)(n0+r)*GD + c];
    }
    __syncthreads();
    float a0 = bm[t], a1 = a0, a2 = a0, a3 = a0;
    for (int c = 0; c < GD; c++) {
        float w1 = Wm[c*GD + t];
        float w2 = Wm[(GD + c)*GD + t];
        float4 xv = *(const float4*)&xs[c][0];
        float4 mv = *(const float4*)&ms[c][0];
        a0 += xv.x*w1 + mv.x*w2; a1 += xv.y*w1 + mv.y*w2;
        a2 += xv.z*w1 + mv.z*w2; a3 += xv.w*w1 + mv.w*w2;
    }
    out[(size_t)(n0+0)*GD + t] = xs[t][0] + a0;
    out[(size_t)(n0+1)*GD + t] = xs[t][1] + a1;
    out[(size_t)(n0+2)*GD + t] = xs[t][2] + a2;
    out[(size_t)(n0+3)*GD + t] = xs[t][3] + a3;
}

// =====================================================================
// proj + l2norm + score
// =====================================================================
__global__ __launch_bounds__(256) void proj_fused(
    const float* __restrict__ g3, const float* __restrict__ Wp,
    const float* __restrict__ bp, const float* __restrict__ Wsc,
    const float* __restrict__ bsc, float* __restrict__ feats,
    float* __restrict__ fnorm, float* __restrict__ scores)
{
    int n = blockIdx.x, t = threadIdx.x;
    __shared__ float xi[GD];
    __shared__ float red[256];
    xi[t] = g3[(size_t)n*GD + t];
    __syncthreads();
    float acc = bp[t];
    for (int c = 0; c < GD; c++) acc += xi[c] * Wp[c*GD + t];
    feats[(size_t)n*GD + t] = acc;
    red[t] = acc * acc; __syncthreads();
    for (int s = 128; s > 0; s >>= 1) { if (t < s) red[t] += red[t+s]; __syncthreads(); }
    float nrm = fmaxf(sqrtf(red[0]), 1e-12f);
    __syncthreads();
    fnorm[(size_t)n*GD + t] = acc / nrm;
    red[t] = acc * Wsc[t]; __syncthreads();
    for (int s = 128; s > 0; s >>= 1) { if (t < s) red[t] += red[t+s]; __syncthreads(); }
    if (t == 0) scores[n] = red[0] + bsc[0];
}

// ip: 4 src rows x 256 tgt cols per block; grid 1024
__global__ __launch_bounds__(256) void ip_kernel(
    const float* __restrict__ fnorm, float* __restrict__ ip)
{
    int t = threadIdx.x;
    int n0 = (blockIdx.x >> 2) * 4;
    int m  = (blockIdx.x & 3) * 256 + t;
    __shared__ float xs[GD][4];
    for (int i = t; i < 4*GD; i += 256) {
        int r = i >> 8, c = i & 255;
        xs[c][r] = fnorm[(size_t)(n0+r)*GD + c];
    }
    __syncthreads();
    const float4* fr = (const float4*)(fnorm + (size_t)(NSRC + m)*GD);
    float a0 = 0.f, a1 = 0.f, a2 = 0.f, a3 = 0.f;
    for (int c4 = 0; c4 < GD/4; c4++) {
        float4 f = fr[c4];
        float4 xa = *(const float4*)&xs[c4*4+0][0];
        float4 xb = *(const float4*)&xs[c4*4+1][0];
        float4 xc = *(const float4*)&xs[c4*4+2][0];
        float4 xd = *(const float4*)&xs[c4*4+3][0];
        a0 += f.x*xa.x + f.y*xb.x + f.z*xc.x + f.w*xd.x;
        a1 += f.x*xa.y + f.y*xb.y + f.z*xc.y + f.w*xd.y;
        a2 += f.x*xa.z + f.y*xb.z + f.z*xc.z + f.w*xd.z;
        a3 += f.x*xa.w + f.y*xb.w + f.z*xc.w + f.w*xd.w;
    }
    ip[(size_t)(n0+0)*NSRC + m] = a0;
    ip[(size_t)(n0+1)*NSRC + m] = a1;
    ip[(size_t)(n0+2)*NSRC + m] = a2;
    ip[(size_t)(n0+3)*NSRC + m] = a3;
}

// saliency
template<bool COL>
__global__ __launch_bounds__(256) void saliency_kernel(
    const float* __restrict__ ip, const float* __restrict__ scores_other,
    const float* __restrict__ epsv, float* __restrict__ sal_out)
{
    int n = blockIdx.x, t = threadIdx.x;
    float T = expf(epsv[0]) + 0.03f;
    __shared__ float red[256];
    float vals[4];
    float m = -INFINITY;
#pragma unroll
    for (int ii = 0; ii < 4; ii++) {
        int i = t + ii*256;
        float vv = COL ? ip[(size_t)i*NSRC + n] : ip[(size_t)n*NSRC + i];
        vv /= T;
        vals[ii] = vv;
        m = fmaxf(m, vv);
    }
    red[t] = m; __syncthreads();
    for (int s = 128; s > 0; s >>= 1) { if (t < s) red[t] = fmaxf(red[t], red[t+s]); __syncthreads(); }
    float mx = red[0]; __syncthreads();
    float se = 0.f, wsum = 0.f;
#pragma unroll
    for (int ii = 0; ii < 4; ii++) {
        int i = t + ii*256;
        float e = expf(vals[ii] - mx);
        se += e; wsum += e * scores_other[i];
    }
    red[t] = se; __syncthreads();
    for (int s = 128; s > 0; s >>= 1) { if (t < s) red[t] += red[t+s]; __syncthreads(); }
    float S = red[0]; __syncthreads();
    red[t] = wsum; __syncthreads();
    for (int s = 128; s > 0; s >>= 1) { if (t < s) red[t] += red[t+s]; __syncthreads(); }
    if (t == 0) sal_out[n] = red[0] / S;
}

// =====================================================================
// decoder — thread per row, W via wave-uniform loads, acc in registers.
// =====================================================================
__global__ __launch_bounds__(256) void decoder_kernel(
    const float* __restrict__ feats, const float* __restrict__ scores,
    const float* __restrict__ sal, const float* __restrict__ skip,
    const int* __restrict__ ups, const float* __restrict__ Wd,
    const float* __restrict__ bd, float* __restrict__ outf,
    float* __restrict__ outso, float* __restrict__ outss)
{
    int row = blockIdx.x * 256 + threadIdx.x;
    if (row >= NFINE) return;
    int u = ups[row];
    float acc[DECOUT];
#pragma unroll
    for (int j = 0; j < DECOUT; j++) acc[j] = bd[j];
    float x0 = scores[u], x1 = sal[u];
#pragma unroll
    for (int j = 0; j < DECOUT; j++) acc[j] += x0 * Wd[j];
#pragma unroll
    for (int j = 0; j < DECOUT; j++) acc[j] += x1 * Wd[DECOUT + j];
    const float4* fr = (const float4*)(feats + (size_t)u * GD);
    for (int c4 = 0; c4 < GD/4; c4++) {
        float4 xv = fr[c4];
        const float* wr = Wd + (size_t)(2 + c4*4) * DECOUT;
#pragma unroll
        for (int j = 0; j < DECOUT; j++) acc[j] += xv.x * wr[j];
#pragma unroll
        for (int j = 0; j < DECOUT; j++) acc[j] += xv.y * wr[DECOUT + j];
#pragma unroll
        for (int j = 0; j < DECOUT; j++) acc[j] += xv.z * wr[2*DECOUT + j];
#pragma unroll
        for (int j = 0; j < DECOUT; j++) acc[j] += xv.w * wr[3*DECOUT + j];
    }
    const float4* sr = (const float4*)(skip + (size_t)row * C1D);
    for (int c4 = 0; c4 < C1D/4; c4++) {
        float4 xv = sr[c4];
        const float* wr = Wd + (size_t)(2 + GD + c4*4) * DECOUT;
#pragma unroll
        for (int j = 0; j < DECOUT; j++) acc[j] += xv.x * wr[j];
#pragma unroll
        for (int j = 0; j < DECOUT; j++) acc[j] += xv.y * wr[DECOUT + j];
#pragma unroll
        for (int j = 0; j < DECOUT; j++) acc[j] += xv.z * wr[2*DECOUT + j];
#pragma unroll
        for (int j = 0; j < DECOUT; j++) acc[j] += xv.w * wr[3*DECOUT + j];
    }
    float sq = 0.f;
#pragma unroll
    for (int j = 0; j < FINALD; j++) sq += acc[j]*acc[j];
    float inv = 1.f / fmaxf(sqrtf(sq), 1e-12f);
    float4* op = (float4*)(outf + (size_t)row * FINALD);
#pragma unroll
    for (int i = 0; i < 8; i++)
        op[i] = make_float4(acc[4*i]*inv, acc[4*i+1]*inv, acc[4*i+2]*inv, acc[4*i+3]*inv);
    float so = 1.f/(1.f + __expf(-acc[32]));
    so = fminf(fmaxf(so, 0.f), 1.f); if (!(so == so)) so = 0.f;
    float ss = 1.f/(1.f + __expf(-acc[33]));
    ss = fminf(fmaxf(ss, 0.f), 1.f); if (!(ss == ss)) ss = 0.f;
    outso[row] = so; outss[row] = ss;
}

// =====================================================================
extern "C" void kernel_launch(void* const* d_in, const int* in_sizes, int n_in,
                              void* d_out, int out_size, void* d_ws, size_t ws_size,
                              hipStream_t stream)
{
    const float* points_f     = (const float*)d_in[0];
    const float* points_c     = (const float*)d_in[1];
    const float* features     = (const float*)d_in[2];
    const float* kp_f         = (const float*)d_in[3];
    const float* kp_c         = (const float*)d_in[4];
    const float* W_kp1        = (const float*)d_in[5];
    const float* W_kp2        = (const float*)d_in[6];
    const float* W_bottle     = (const float*)d_in[7];
    const float* b_bottle     = (const float*)d_in[8];
    const float* W_self1      = (const float*)d_in[9];
    const float* b_self1      = (const float*)d_in[10];
    const float* Wq           = (const float*)d_in[11];
    const float* Wk           = (const float*)d_in[12];
    const float* Wv           = (const float*)d_in[13];
    const float* W_cross      = (const float*)d_in[14];
    const float* b_cross      = (const float*)d_in[15];
    const float* W_self2      = (const float*)d_in[16];
    const float* b_self2      = (const float*)d_in[17];
    const float* W_proj       = (const float*)d_in[18];
    const float* b_proj       = (const float*)d_in[19];
    const float* W_score      = (const float*)d_in[20];
    const float* b_score      = (const float*)d_in[21];
    const float* epsilon      = (const float*)d_in[22];
    const float* W_dec        = (const float*)d_in[23];
    const float* b_dec        = (const float*)d_in[24];
    const int*   neighbors_f  = (const int*)d_in[25];
    const int*   pool_idx     = (const int*)d_in[26];
    const int*   upsample_idx = (const int*)d_in[27];

    float* ws = (float*)d_ws;
    size_t o = 0;
    auto alloc = [&](size_t nfl) { float* p = ws + o; o += (nfl + 63) & ~(size_t)63; return p; };
    float* x_f     = alloc((size_t)NFINE * C1D);
    float* g1      = alloc((size_t)NCRS * GD);
    float* qb      = alloc((size_t)NCRS * GD);
    float* kb      = alloc((size_t)NCRS * GD);
    float* vb      = alloc((size_t)NCRS * GD);
    float* msg     = alloc((size_t)NCRS * GD);
    float* feats_c = alloc((size_t)NCRS * GD);
    float* scores  = alloc(NCRS);
    float* sal     = alloc(NCRS);
    int*   knn_b   = (int*)alloc(NCRS * DGK);

    // Union region: phases reuse the same memory (lifetimes are disjoint).
    const size_t NG = (size_t)NCRS * GD;          // 524288
    size_t usz = (size_t)NCRS*C2D + (size_t)NCRS*KP*C1D;   // x_c + hhg = 4,456,448
    float* U = alloc(usz);
    // encoder phase
    float* x_c  = U;                              // [hh gemm -> bottleneck)
    float* hhg  = U + (size_t)NCRS*C2D;           // [hh_kernel -> gemm)
    // self1 phase
    float* Y1   = U;                              // [self_gemm1 -> edge_max1)
    // attention phase
    float* pm   = U;
    float* pl   = U + (size_t)NCRS*4*NCHUNK;
    float* pacc = U + (size_t)2*NCRS*4*NCHUNK;    // 4.19M floats
    // post-attention phase
    float* g2   = U;                              // [cross -> self_gemm2)
    float* Y2   = U + NG;                         // [self_gemm2 -> edge_max2)
    float* g3   = U + 3*NG;                       // [edge_max2 -> proj)
    float* feats= U + 4*NG;                       // [proj -> decoder)
    float* fnorm= U + 5*NG;                       // [proj -> ip)
    float* ip   = U + 6*NG;                       // [ip -> saliency)

    float* outf  = (float*)d_out;
    float* outso = outf + (size_t)NFINE * FINALD;
    float* outss = outso + NFINE;

    // encoder
    kpconv_fine<<<NFINE/4, 256, 0, stream>>>(points_f, features, neighbors_f, kp_f, W_kp1, x_f);
    hh_kernel<<<NCRS, 256, 0, stream>>>(points_c, points_f, x_f, pool_idx, kp_c, hhg);
    linear_rows<KP*C1D, C2D, 4, false><<<NCRS/4, C2D, 0, stream>>>(hhg, W_kp2, nullptr, x_c);
    linear_rows<C2D, GD, 4, true><<<NCRS/4, GD, 0, stream>>>(x_c, W_bottle, b_bottle, feats_c);

    // GNN
    knn_kernel<<<NCRS, 256, 0, stream>>>(points_c, knn_b);
    self_gemm<<<NCRS/4, 512, 0, stream>>>(feats_c, W_self1, Y1);
    edge_max<<<NCRS, 256, 0, stream>>>(Y1, knn_b, b_self1, g1);
    qkv_kernel<<<NCRS/4, 256, 0, stream>>>(g1, Wq, Wk, Wv, qb, kb, vb);
    attn_flash<<<256, 256, 0, stream>>>(qb, kb, vb, pm, pl, pacc);
    attn_combine<<<NCRS, 256, 0, stream>>>(pm, pl, pacc, msg);
    cross_combine<<<NCRS/4, 256, 0, stream>>>(g1, msg, W_cross, b_cross, g2);
    self_gemm<<<NCRS/4, 512, 0, stream>>>(g2, W_self2, Y2);
    edge_max<<<NCRS, 256, 0, stream>>>(Y2, knn_b, b_self2, g3);

    // head
    proj_fused<<<NCRS, 256, 0, stream>>>(g3, W_proj, b_proj, W_score, b_score, feats, fnorm, scores);
    ip_kernel<<<NSRC, 256, 0, stream>>>(fnorm, ip);
    saliency_kernel<false><<<NSRC, 256, 0, stream>>>(ip, scores + NSRC, epsilon, sal);
    saliency_kernel<true><<<NSRC, 256, 0, stream>>>(ip, scores, epsilon, sal + NSRC);

    // decoder
    decoder_kernel<<<(NFINE + 255)/256, 256, 0, stream>>>(feats, scores, sal, x_f, upsample_idx,
                                                          W_dec, b_dec, outf, outso, outss);
}

// Round 6
// 493.000 us; speedup vs baseline: 3.7686x; 1.1050x over previous
//
#include <hip/hip_runtime.h>
#include <math.h>

// ---- problem constants ----
#define NFINE   80000
#define NCRS    2048
#define NSRC    1024
#define NNB     30
#define KP      15
#define C1D     128
#define C2D     256
#define GD      256
#define DGK     10
#define FINALD  32
#define DECIN   386
#define DECOUT  34

#define NCHUNK  8      // attention key-split
#define CHUNK   128    // 1024 / NCHUNK
#define TK      32     // attention LDS key tile

// =====================================================================
// Stage 1: kpconv fine — one wave per point, 4 points per block.
// contrib padded to 17 floats: stride coprime with 32 banks.
// =====================================================================
__global__ __launch_bounds__(256) void kpconv_fine(
    const float* __restrict__ pts, const float* __restrict__ feat,
    const int* __restrict__ nbr, const float* __restrict__ kp,
    const float* __restrict__ W, float* __restrict__ out)
{
    int t = threadIdx.x, w = t >> 6, lane = t & 63;
    int n = blockIdx.x * 4 + w;
    __shared__ float contrib[4][NNB][17];
    __shared__ float h[4][KP + 1];
    float kx[KP], ky[KP], kz[KP], kk[KP];
#pragma unroll
    for (int k = 0; k < KP; k++) {
        kx[k] = kp[k*3]; ky[k] = kp[k*3+1]; kz[k] = kp[k*3+2];
        kk[k] = kx[k]*kx[k] + ky[k]*ky[k] + kz[k]*kz[k];
    }
    if (lane < NNB) {
        float qx = pts[n*3], qy = pts[n*3+1], qz = pts[n*3+2];
        int id = nbr[n*NNB + lane];
        float rx = pts[id*3]-qx, ry = pts[id*3+1]-qy, rz = pts[id*3+2]-qz;
        float rr = rx*rx + ry*ry + rz*rz;
        float f = feat[id];
#pragma unroll
        for (int k = 0; k < KP; k++) {
            float d2 = rr + kk[k] - 2.f*(rx*kx[k] + ry*ky[k] + rz*kz[k]);
            float infl = fmaxf(1.f - sqrtf(fmaxf(d2, 1e-12f)), 0.f); // extent=1
            contrib[w][lane][k] = infl * f;
        }
    }
    __syncthreads();
    if (lane < KP) {
        float s = 0.f;
#pragma unroll
        for (int j = 0; j < NNB; j++) s += contrib[w][j][lane];
        h[w][lane] = s;
    }
    __syncthreads();
    float a0 = 0.f, a1 = 0.f;
#pragma unroll
    for (int k = 0; k < KP; k++) {
        float hk = h[w][k];
        a0 += hk * W[k*C1D + lane];
        a1 += hk * W[k*C1D + 64 + lane];
    }
    out[(size_t)n*C1D + lane]      = a0;
    out[(size_t)n*C1D + 64 + lane] = a1;
}

// =====================================================================
// Stage 2a: hh for each coarse point -> global (2048 blocks, high TLP)
// =====================================================================
__global__ __launch_bounds__(256) void hh_kernel(
    const float* __restrict__ pc, const float* __restrict__ pf,
    const float* __restrict__ xf, const int* __restrict__ pool,
    const float* __restrict__ kp, float* __restrict__ hhg)
{
    int n = blockIdx.x, t = threadIdx.x;
    __shared__ float kx[KP], ky[KP], kz[KP], kk[KP];
    __shared__ float rel[NNB][4];
    __shared__ int   ids[NNB];
    __shared__ float infl[NNB][KP + 1];
    __shared__ float nf[NNB][C1D];
    if (t < KP) {
        float a = kp[t*3], b = kp[t*3+1], c = kp[t*3+2];
        kx[t] = a; ky[t] = b; kz[t] = c; kk[t] = a*a + b*b + c*c;
    }
    if (t < NNB) {
        int id = pool[n*NNB + t]; ids[t] = id;
        float qx = pc[n*3], qy = pc[n*3+1], qz = pc[n*3+2];
        float rx = pf[id*3]-qx, ry = pf[id*3+1]-qy, rz = pf[id*3+2]-qz;
        rel[t][0] = rx; rel[t][1] = ry; rel[t][2] = rz;
        rel[t][3] = rx*rx + ry*ry + rz*rz;
    }
    __syncthreads();
    for (int i = t; i < NNB*KP; i += 256) {
        int j = i / KP, kq = i % KP;
        float d2 = rel[j][3] + kk[kq]
                 - 2.f*(rel[j][0]*kx[kq] + rel[j][1]*ky[kq] + rel[j][2]*kz[kq]);
        infl[j][kq] = fmaxf(1.f - sqrtf(fmaxf(d2, 1e-12f)) * 0.5f, 0.f); // extent=2
    }
    for (int i = t; i < NNB*C1D; i += 256) {
        int j = i >> 7, c = i & 127;
        nf[j][c] = xf[(size_t)ids[j]*C1D + c];
    }
    __syncthreads();
    for (int i = t; i < KP*C1D; i += 256) {
        int kq = i >> 7, c = i & 127;
        float s = 0.f;
#pragma unroll
        for (int j = 0; j < NNB; j++) s += infl[j][kq] * nf[j][c];
        hhg[(size_t)n*(KP*C1D) + i] = s;
    }
}

// =====================================================================
// Generic row-tiled linear: TR rows/block, COUT threads.
// =====================================================================
template<int CIN, int COUT, int TR, bool BIAS>
__global__ __launch_bounds__(COUT) void linear_rows(
    const float* __restrict__ in, const float* __restrict__ W,
    const float* __restrict__ b, float* __restrict__ out)
{
    int t = threadIdx.x, n0 = blockIdx.x * TR;
    __shared__ float xi[CIN][TR];
    for (int i = t; i < TR*CIN; i += COUT) {
        int r = i / CIN, c = i % CIN;
        xi[c][r] = in[(size_t)(n0+r)*CIN + c];
    }
    __syncthreads();
    float a[TR];
#pragma unroll
    for (int r = 0; r < TR; r++) a[r] = BIAS ? b[t] : 0.f;
    for (int c = 0; c < CIN; c++) {
        float wv = W[(size_t)c*COUT + t];
        float4 x0 = *(const float4*)&xi[c][0];
        a[0] += x0.x*wv; a[1] += x0.y*wv; a[2] += x0.z*wv; a[3] += x0.w*wv;
    }
#pragma unroll
    for (int r = 0; r < TR; r++) out[(size_t)(n0+r)*COUT + t] = a[r];
}

// =====================================================================
// self-layer GEMM: Y[n] = X[n]@[W1|W2]  (512 cols)
// =====================================================================
__global__ __launch_bounds__(512) void self_gemm(
    const float* __restrict__ x, const float* __restrict__ W,
    float* __restrict__ Y)
{
    int t = threadIdx.x, n0 = blockIdx.x * 4;
    __shared__ float xi[GD][4];
    for (int i = t; i < 4*GD; i += 512) {
        int r = i >> 8, c = i & 255;
        xi[c][r] = x[(size_t)(n0+r)*GD + c];
    }
    __syncthreads();
    const float* wcol = (t < GD) ? (W + t) : (W + (size_t)GD*GD + (t - GD));
    float a0 = 0.f, a1 = 0.f, a2 = 0.f, a3 = 0.f;
    for (int c = 0; c < GD; c++) {
        float wv = wcol[(size_t)c*GD];
        float4 xv = *(const float4*)&xi[c][0];
        a0 += xv.x*wv; a1 += xv.y*wv; a2 += xv.z*wv; a3 += xv.w*wv;
    }
    Y[(size_t)(n0+0)*512 + t] = a0;
    Y[(size_t)(n0+1)*512 + t] = a1;
    Y[(size_t)(n0+2)*512 + t] = a2;
    Y[(size_t)(n0+3)*512 + t] = a3;
}

// edge conv max: out[n][t] = max_j relu(A[n][t] - B[n][t] + B[idx_j][t] + b[t])
__global__ __launch_bounds__(256) void edge_max(
    const float* __restrict__ Y, const int* __restrict__ knn,
    const float* __restrict__ b, float* __restrict__ out)
{
    int n = blockIdx.x, t = threadIdx.x;
    int base = (n < NSRC) ? 0 : NSRC;
    __shared__ int ids[DGK];
    if (t < DGK) ids[t] = base + knn[n*DGK + t];
    __syncthreads();
    float a  = Y[(size_t)n*512 + t];
    float bn = Y[(size_t)n*512 + GD + t];
    float cst = a - bn + b[t];
    float acc = 0.f;
#pragma unroll
    for (int j = 0; j < DGK; j++) {
        float bj = Y[(size_t)ids[j]*512 + GD + t];
        acc = fmaxf(acc, fmaxf(cst + bj, 0.f));
    }
    out[(size_t)n*GD + t] = acc;
}

// fused q,k,v projections, 4 rows per block
__global__ __launch_bounds__(256) void qkv_kernel(
    const float* __restrict__ x, const float* __restrict__ Wq,
    const float* __restrict__ Wk, const float* __restrict__ Wv,
    float* __restrict__ qb, float* __restrict__ kb, float* __restrict__ vb)
{
    int t = threadIdx.x, n0 = blockIdx.x * 4;
    __shared__ float xi[GD][4];
    for (int i = t; i < 4*GD; i += 256) {
        int r = i >> 8, c = i & 255;
        xi[c][r] = x[(size_t)(n0+r)*GD + c];
    }
    __syncthreads();
    const float* Ws[3] = {Wq, Wk, Wv};
    float* outs[3] = {qb, kb, vb};
#pragma unroll
    for (int m = 0; m < 3; m++) {
        const float* W = Ws[m];
        float a0 = 0.f, a1 = 0.f, a2 = 0.f, a3 = 0.f;
        for (int c = 0; c < GD; c++) {
            float wv = W[c*GD + t];
            float4 xv = *(const float4*)&xi[c][0];
            a0 += xv.x*wv; a1 += xv.y*wv; a2 += xv.z*wv; a3 += xv.w*wv;
        }
        float* o = outs[m];
        o[(size_t)(n0+0)*GD + t] = a0;
        o[(size_t)(n0+1)*GD + t] = a1;
        o[(size_t)(n0+2)*GD + t] = a2;
        o[(size_t)(n0+3)*GD + t] = a3;
    }
}

// =====================================================================
// knn — block per query, LDS d2 + 10 deterministic min-selections.
// =====================================================================
__global__ __launch_bounds__(256) void knn_kernel(
    const float* __restrict__ pts, int* __restrict__ knn)
{
    int g = blockIdx.x;            // query 0..2047
    int t = threadIdx.x;
    int base = (g < NSRC) ? 0 : NSRC;
    int local = g - base;
    const float* P = pts + (size_t)base*3;
    __shared__ float d2s[NSRC];
    __shared__ float wval[4];
    __shared__ int   widx[4];
    float qx = P[local*3], qy = P[local*3+1], qz = P[local*3+2];
    float sqn = qx*qx + qy*qy + qz*qz;
#pragma unroll
    for (int ii = 0; ii < 4; ii++) {
        int m = t + ii*256;
        float px = P[m*3], py = P[m*3+1], pz = P[m*3+2];
        float sqm = px*px + py*py + pz*pz;
        d2s[m] = sqn + sqm - 2.f*(qx*px + qy*py + qz*pz);
    }
    __syncthreads();
    for (int r = 0; r < DGK; r++) {
        float bv = 3.4e38f; int bidx = NSRC;
#pragma unroll
        for (int ii = 0; ii < 4; ii++) {
            int m = t + ii*256;
            float v = d2s[m];
            if (v < bv) { bv = v; bidx = m; }   // ascending m: ties keep lower
        }
#pragma unroll
        for (int off = 32; off >= 1; off >>= 1) {
            float ov = __shfl_xor(bv, off);
            int   oi = __shfl_xor(bidx, off);
            if (ov < bv || (ov == bv && oi < bidx)) { bv = ov; bidx = oi; }
        }
        if ((t & 63) == 0) { wval[t >> 6] = bv; widx[t >> 6] = bidx; }
        __syncthreads();
        if (t == 0) {
            float fv = wval[0]; int fi = widx[0];
#pragma unroll
            for (int wv2 = 1; wv2 < 4; wv2++)
                if (wval[wv2] < fv || (wval[wv2] == fv && widx[wv2] < fi)) {
                    fv = wval[wv2]; fi = widx[wv2];
                }
            knn[g*DGK + r] = fi;
            d2s[fi] = 3.4e38f;
        }
        __syncthreads();
    }
}

// =====================================================================
// attention: flash with LDS K/V staging; each (row,head,chunk) unit is
// handled by 4 lanes (16 dims each) -> 1024 blocks, 4 blocks/CU.
// =====================================================================
__global__ __launch_bounds__(256) void attn_flash(
    const float* __restrict__ qb, const float* __restrict__ kb,
    const float* __restrict__ vb, float* __restrict__ pm,
    float* __restrict__ pl, float* __restrict__ pacc)
{
    int bidx = blockIdx.x;
    int h = bidx & 3, chunk = (bidx >> 2) & 7, rb = bidx >> 5;  // rb 0..31
    int t = threadIdx.x;
    int u = t >> 2, li = t & 3;        // unit (row) and lane-in-unit
    int row = rb * 64 + u;
    int kbase = (row < NSRC) ? NSRC : 0;   // uniform across block (64-row tiles)

    __shared__ float4 kt[2][TK][16];
    __shared__ float4 vt[2][TK][16];

    const float4* kb4 = (const float4*)kb;
    const float4* vb4 = (const float4*)vb;
    size_t gbase = ((size_t)(kbase + chunk*CHUNK)) * 64 + h*16;

    // q slice: 16 floats at offset h*64 + li*16
    float4 q[4];
    const float4* q4 = (const float4*)(qb + (size_t)row*GD + h*64 + li*16);
#pragma unroll
    for (int i = 0; i < 4; i++) q[i] = q4[i];
    float4 a[4];
#pragma unroll
    for (int i = 0; i < 4; i++) a[i] = make_float4(0.f, 0.f, 0.f, 0.f);
    float mr = -INFINITY, lr = 0.f;

    int f0 = t, f1 = t + 256;          // flat float4 idx: key=f>>4, comp=f&15
    float4 rk0, rk1, rv0, rv1;

    // prologue: stage tile 0
    {
        size_t tb = gbase;
        rk0 = kb4[tb + (size_t)(f0>>4)*64 + (f0&15)];
        rk1 = kb4[tb + (size_t)(f1>>4)*64 + (f1&15)];
        rv0 = vb4[tb + (size_t)(f0>>4)*64 + (f0&15)];
        rv1 = vb4[tb + (size_t)(f1>>4)*64 + (f1&15)];
        kt[0][f0>>4][f0&15] = rk0;  kt[0][f1>>4][f1&15] = rk1;
        vt[0][f0>>4][f0&15] = rv0;  vt[0][f1>>4][f1&15] = rv1;
    }
    __syncthreads();

    const int NT = CHUNK / TK;   // 4
    for (int tile = 0; tile < NT; tile++) {
        int cur = tile & 1;
        if (tile + 1 < NT) {     // issue next tile's loads (hide under compute)
            size_t tb = gbase + (size_t)(tile+1)*TK*64;
            rk0 = kb4[tb + (size_t)(f0>>4)*64 + (f0&15)];
            rk1 = kb4[tb + (size_t)(f1>>4)*64 + (f1&15)];
            rv0 = vb4[tb + (size_t)(f0>>4)*64 + (f0&15)];
            rv1 = vb4[tb + (size_t)(f1>>4)*64 + (f1&15)];
        }
#pragma unroll 4
        for (int j = 0; j < TK; j++) {
            float4 k0 = kt[cur][j][li*4+0];
            float4 k1 = kt[cur][j][li*4+1];
            float4 k2 = kt[cur][j][li*4+2];
            float4 k3 = kt[cur][j][li*4+3];
            float d0 = q[0].x*k0.x + q[0].y*k0.y + q[0].z*k0.z + q[0].w*k0.w;
            float d1 = q[1].x*k1.x + q[1].y*k1.y + q[1].z*k1.z + q[1].w*k1.w;
            float d2 = q[2].x*k2.x + q[2].y*k2.y + q[2].z*k2.z + q[2].w*k2.w;
            float d3 = q[3].x*k3.x + q[3].y*k3.y + q[3].z*k3.z + q[3].w*k3.w;
            float p = (d0 + d1) + (d2 + d3);
            p += __shfl_xor(p, 1);     // reduce across the 4-lane group
            p += __shfl_xor(p, 2);
            p *= 0.125f;               // 1/sqrt(64)
            float mn = fmaxf(mr, p);
            float sc = __expf(mr - mn);
            float e  = __expf(p - mn);
            lr = lr*sc + e;
            float4 v0 = vt[cur][j][li*4+0];
            float4 v1 = vt[cur][j][li*4+1];
            float4 v2 = vt[cur][j][li*4+2];
            float4 v3 = vt[cur][j][li*4+3];
            a[0].x = a[0].x*sc + e*v0.x; a[0].y = a[0].y*sc + e*v0.y;
            a[0].z = a[0].z*sc + e*v0.z; a[0].w = a[0].w*sc + e*v0.w;
            a[1].x = a[1].x*sc + e*v1.x; a[1].y = a[1].y*sc + e*v1.y;
            a[1].z = a[1].z*sc + e*v1.z; a[1].w = a[1].w*sc + e*v1.w;
            a[2].x = a[2].x*sc + e*v2.x; a[2].y = a[2].y*sc + e*v2.y;
            a[2].z = a[2].z*sc + e*v2.z; a[2].w = a[2].w*sc + e*v2.w;
            a[3].x = a[3].x*sc + e*v3.x; a[3].y = a[3].y*sc + e*v3.y;
            a[3].z = a[3].z*sc + e*v3.z; a[3].w = a[3].w*sc + e*v3.w;
            mr = mn;
        }
        if (tile + 1 < NT) {
            __syncthreads();           // all waves done reading
            int nb = (tile + 1) & 1;
            kt[nb][f0>>4][f0&15] = rk0;  kt[nb][f1>>4][f1&15] = rk1;
            vt[nb][f0>>4][f0&15] = rv0;  vt[nb][f1>>4][f1&15] = rv1;
            __syncthreads();           // writes visible before next compute
        }
    }
    int pi = (chunk*4 + h)*NCRS + row;
    if (li == 0) { pm[pi] = mr; pl[pi] = lr; }
    float4* po = (float4*)(pacc + (size_t)pi*64);
#pragma unroll
    for (int i = 0; i < 4; i++) po[li*4 + i] = a[i];
}

__global__ __launch_bounds__(256) void attn_combine(
    const float* __restrict__ pm, const float* __restrict__ pl,
    const float* __restrict__ pacc, float* __restrict__ msg)
{
    int row = blockIdx.x, t = threadIdx.x;
    int h = t >> 6, d = t & 63;
    float m = -INFINITY;
#pragma unroll
    for (int c = 0; c < NCHUNK; c++) m = fmaxf(m, pm[(c*4 + h)*NCRS + row]);
    float lsum = 0.f, asum = 0.f;
#pragma unroll
    for (int c = 0; c < NCHUNK; c++) {
        int pi = (c*4 + h)*NCRS + row;
        float w = __expf(pm[pi] - m);
        lsum += pl[pi] * w;
        asum += pacc[(size_t)pi*64 + d] * w;
    }
    msg[(size_t)row*GD + h*64 + d] = asum / lsum;
}

// out = x + [x, msg] @ Wm + bm, 4 rows/block
__global__ __launch_bounds__(256) void cross_combine(
    const float* __restrict__ x, const float* __restrict__ msg,
    const float* __restrict__ Wm, const float* __restrict__ bm,
    float* __restrict__ out)
{
    int t = threadIdx.x, n0 = blockIdx.x * 4;
    __shared__ float xs[GD][4], ms[GD][4];
    for (int i = t; i < 4*GD; i += 256) {
        int r = i >> 8, c = i & 255;
        xs[c][r] = x[(size_t)(n0+r)*GD + c];
        ms[c][r] = msg[(size_t)(n0+r)*GD + c];
    }
    __syncthreads();
    float a0 = bm[t], a1 = a0, a2 = a0, a3 = a0;
    for (int c = 0; c < GD; c++) {
        float w1 = Wm[c*GD + t];
        float w2 = Wm[(GD + c)*GD + t];
        float4 xv = *(const float4*)&xs[c][0];
        float4 mv = *(const float4*)&ms[c][0];
        a0 += xv.x*w1 + mv.x*w2; a1 += xv.y*w1 + mv.y*w2;
        a2 += xv.z*w1 + mv.z*w2; a3 += xv.w*w1 + mv.w*w2;
    }
    out[(size_t)(n0+0)*GD + t] = xs[t][0] + a0;
    out[(size_t)(n0+1)*GD + t] = xs[t][1] + a1;
    out[(size_t)(n0+2)*GD + t] = xs[t][2] + a2;
    out[(size_t)(n0+3)*GD + t] = xs[t][3] + a3;
}

// =====================================================================
// proj + l2norm + score
// =====================================================================
__global__ __launch_bounds__(256) void proj_fused(
    const float* __restrict__ g3, const float* __restrict__ Wp,
    const float* __restrict__ bp, const float* __restrict__ Wsc,
    const float* __restrict__ bsc, float* __restrict__ feats,
    float* __restrict__ fnorm, float* __restrict__ scores)
{
    int n = blockIdx.x, t = threadIdx.x;
    __shared__ float xi[GD];
    __shared__ float red[256];
    xi[t] = g3[(size_t)n*GD + t];
    __syncthreads();
    float acc = bp[t];
    for (int c = 0; c < GD; c++) acc += xi[c] * Wp[c*GD + t];
    feats[(size_t)n*GD + t] = acc;
    red[t] = acc * acc; __syncthreads();
    for (int s = 128; s > 0; s >>= 1) { if (t < s) red[t] += red[t+s]; __syncthreads(); }
    float nrm = fmaxf(sqrtf(red[0]), 1e-12f);
    __syncthreads();
    fnorm[(size_t)n*GD + t] = acc / nrm;
    red[t] = acc * Wsc[t]; __syncthreads();
    for (int s = 128; s > 0; s >>= 1) { if (t < s) red[t] += red[t+s]; __syncthreads(); }
    if (t == 0) scores[n] = red[0] + bsc[0];
}

// ip: 4 src rows x 256 tgt cols per block; grid 1024
__global__ __launch_bounds__(256) void ip_kernel(
    const float* __restrict__ fnorm, float* __restrict__ ip)
{
    int t = threadIdx.x;
    int n0 = (blockIdx.x >> 2) * 4;
    int m  = (blockIdx.x & 3) * 256 + t;
    __shared__ float xs[GD][4];
    for (int i = t; i < 4*GD; i += 256) {
        int r = i >> 8, c = i & 255;
        xs[c][r] = fnorm[(size_t)(n0+r)*GD + c];
    }
    __syncthreads();
    const float4* fr = (const float4*)(fnorm + (size_t)(NSRC + m)*GD);
    float a0 = 0.f, a1 = 0.f, a2 = 0.f, a3 = 0.f;
    for (int c4 = 0; c4 < GD/4; c4++) {
        float4 f = fr[c4];
        float4 xa = *(const float4*)&xs[c4*4+0][0];
        float4 xb = *(const float4*)&xs[c4*4+1][0];
        float4 xc = *(const float4*)&xs[c4*4+2][0];
        float4 xd = *(const float4*)&xs[c4*4+3][0];
        a0 += f.x*xa.x + f.y*xb.x + f.z*xc.x + f.w*xd.x;
        a1 += f.x*xa.y + f.y*xb.y + f.z*xc.y + f.w*xd.y;
        a2 += f.x*xa.z + f.y*xb.z + f.z*xc.z + f.w*xd.z;
        a3 += f.x*xa.w + f.y*xb.w + f.z*xc.w + f.w*xd.w;
    }
    ip[(size_t)(n0+0)*NSRC + m] = a0;
    ip[(size_t)(n0+1)*NSRC + m] = a1;
    ip[(size_t)(n0+2)*NSRC + m] = a2;
    ip[(size_t)(n0+3)*NSRC + m] = a3;
}

// saliency
template<bool COL>
__global__ __launch_bounds__(256) void saliency_kernel(
    const float* __restrict__ ip, const float* __restrict__ scores_other,
    const float* __restrict__ epsv, float* __restrict__ sal_out)
{
    int n = blockIdx.x, t = threadIdx.x;
    float T = expf(epsv[0]) + 0.03f;
    __shared__ float red[256];
    float vals[4];
    float m = -INFINITY;
#pragma unroll
    for (int ii = 0; ii < 4; ii++) {
        int i = t + ii*256;
        float vv = COL ? ip[(size_t)i*NSRC + n] : ip[(size_t)n*NSRC + i];
        vv /= T;
        vals[ii] = vv;
        m = fmaxf(m, vv);
    }
    red[t] = m; __syncthreads();
    for (int s = 128; s > 0; s >>= 1) { if (t < s) red[t] = fmaxf(red[t], red[t+s]); __syncthreads(); }
    float mx = red[0]; __syncthreads();
    float se = 0.f, wsum = 0.f;
#pragma unroll
    for (int ii = 0; ii < 4; ii++) {
        int i = t + ii*256;
        float e = expf(vals[ii] - mx);
        se += e; wsum += e * scores_other[i];
    }
    red[t] = se; __syncthreads();
    for (int s = 128; s > 0; s >>= 1) { if (t < s) red[t] += red[t+s]; __syncthreads(); }
    float S = red[0]; __syncthreads();
    red[t] = wsum; __syncthreads();
    for (int s = 128; s > 0; s >>= 1) { if (t < s) red[t] += red[t+s]; __syncthreads(); }
    if (t == 0) sal_out[n] = red[0] / S;
}

// =====================================================================
// decoder — thread per row, W via wave-uniform loads, acc in registers.
// =====================================================================
__global__ __launch_bounds__(256) void decoder_kernel(
    const float* __restrict__ feats, const float* __restrict__ scores,
    const float* __restrict__ sal, const float* __restrict__ skip,
    const int* __restrict__ ups, const float* __restrict__ Wd,
    const float* __restrict__ bd, float* __restrict__ outf,
    float* __restrict__ outso, float* __restrict__ outss)
{
    int row = blockIdx.x * 256 + threadIdx.x;
    if (row >= NFINE) return;
    int u = ups[row];
    float acc[DECOUT];
#pragma unroll
    for (int j = 0; j < DECOUT; j++) acc[j] = bd[j];
    float x0 = scores[u], x1 = sal[u];
#pragma unroll
    for (int j = 0; j < DECOUT; j++) acc[j] += x0 * Wd[j];
#pragma unroll
    for (int j = 0; j < DECOUT; j++) acc[j] += x1 * Wd[DECOUT + j];
    const float4* fr = (const float4*)(feats + (size_t)u * GD);
    for (int c4 = 0; c4 < GD/4; c4++) {
        float4 xv = fr[c4];
        const float* wr = Wd + (size_t)(2 + c4*4) * DECOUT;
#pragma unroll
        for (int j = 0; j < DECOUT; j++) acc[j] += xv.x * wr[j];
#pragma unroll
        for (int j = 0; j < DECOUT; j++) acc[j] += xv.y * wr[DECOUT + j];
#pragma unroll
        for (int j = 0; j < DECOUT; j++) acc[j] += xv.z * wr[2*DECOUT + j];
#pragma unroll
        for (int j = 0; j < DECOUT; j++) acc[j] += xv.w * wr[3*DECOUT + j];
    }
    const float4* sr = (const float4*)(skip + (size_t)row * C1D);
    for (int c4 = 0; c4 < C1D/4; c4++) {
        float4 xv = sr[c4];
        const float* wr = Wd + (size_t)(2 + GD + c4*4) * DECOUT;
#pragma unroll
        for (int j = 0; j < DECOUT; j++) acc[j] += xv.x * wr[j];
#pragma unroll
        for (int j = 0; j < DECOUT; j++) acc[j] += xv.y * wr[DECOUT + j];
#pragma unroll
        for (int j = 0; j < DECOUT; j++) acc[j] += xv.z * wr[2*DECOUT + j];
#pragma unroll
        for (int j = 0; j < DECOUT; j++) acc[j] += xv.w * wr[3*DECOUT + j];
    }
    float sq = 0.f;
#pragma unroll
    for (int j = 0; j < FINALD; j++) sq += acc[j]*acc[j];
    float inv = 1.f / fmaxf(sqrtf(sq), 1e-12f);
    float4* op = (float4*)(outf + (size_t)row * FINALD);
#pragma unroll
    for (int i = 0; i < 8; i++)
        op[i] = make_float4(acc[4*i]*inv, acc[4*i+1]*inv, acc[4*i+2]*inv, acc[4*i+3]*inv);
    float so = 1.f/(1.f + __expf(-acc[32]));
    so = fminf(fmaxf(so, 0.f), 1.f); if (!(so == so)) so = 0.f;
    float ss = 1.f/(1.f + __expf(-acc[33]));
    ss = fminf(fmaxf(ss, 0.f), 1.f); if (!(ss == ss)) ss = 0.f;
    outso[row] = so; outss[row] = ss;
}

// =====================================================================
extern "C" void kernel_launch(void* const* d_in, const int* in_sizes, int n_in,
                              void* d_out, int out_size, void* d_ws, size_t ws_size,
                              hipStream_t stream)
{
    const float* points_f     = (const float*)d_in[0];
    const float* points_c     = (const float*)d_in[1];
    const float* features     = (const float*)d_in[2];
    const float* kp_f         = (const float*)d_in[3];
    const float* kp_c         = (const float*)d_in[4];
    const float* W_kp1        = (const float*)d_in[5];
    const float* W_kp2        = (const float*)d_in[6];
    const float* W_bottle     = (const float*)d_in[7];
    const float* b_bottle     = (const float*)d_in[8];
    const float* W_self1      = (const float*)d_in[9];
    const float* b_self1      = (const float*)d_in[10];
    const float* Wq           = (const float*)d_in[11];
    const float* Wk           = (const float*)d_in[12];
    const float* Wv           = (const float*)d_in[13];
    const float* W_cross      = (const float*)d_in[14];
    const float* b_cross      = (const float*)d_in[15];
    const float* W_self2      = (const float*)d_in[16];
    const float* b_self2      = (const float*)d_in[17];
    const float* W_proj       = (const float*)d_in[18];
    const float* b_proj       = (const float*)d_in[19];
    const float* W_score      = (const float*)d_in[20];
    const float* b_score      = (const float*)d_in[21];
    const float* epsilon      = (const float*)d_in[22];
    const float* W_dec        = (const float*)d_in[23];
    const float* b_dec        = (const float*)d_in[24];
    const int*   neighbors_f  = (const int*)d_in[25];
    const int*   pool_idx     = (const int*)d_in[26];
    const int*   upsample_idx = (const int*)d_in[27];

    float* ws = (float*)d_ws;
    size_t o = 0;
    auto alloc = [&](size_t nfl) { float* p = ws + o; o += (nfl + 63) & ~(size_t)63; return p; };
    float* x_f     = alloc((size_t)NFINE * C1D);
    float* g1      = alloc((size_t)NCRS * GD);
    float* qb      = alloc((size_t)NCRS * GD);
    float* kb      = alloc((size_t)NCRS * GD);
    float* vb      = alloc((size_t)NCRS * GD);
    float* msg     = alloc((size_t)NCRS * GD);
    float* feats_c = alloc((size_t)NCRS * GD);
    float* scores  = alloc(NCRS);
    float* sal     = alloc(NCRS);
    int*   knn_b   = (int*)alloc(NCRS * DGK);

    // Union region: phases reuse the same memory (lifetimes are disjoint).
    const size_t NG = (size_t)NCRS * GD;          // 524288
    size_t usz = (size_t)NCRS*C2D + (size_t)NCRS*KP*C1D;   // x_c + hhg = 4,456,448
    float* U = alloc(usz);
    // encoder phase
    float* x_c  = U;                              // [hh gemm -> bottleneck)
    float* hhg  = U + (size_t)NCRS*C2D;           // [hh_kernel -> gemm)
    // self1 phase
    float* Y1   = U;                              // [self_gemm1 -> edge_max1)
    // attention phase
    float* pm   = U;
    float* pl   = U + (size_t)NCRS*4*NCHUNK;
    float* pacc = U + (size_t)2*NCRS*4*NCHUNK;    // 4.19M floats
    // post-attention phase
    float* g2   = U;                              // [cross -> self_gemm2)
    float* Y2   = U + NG;                         // [self_gemm2 -> edge_max2)
    float* g3   = U + 3*NG;                       // [edge_max2 -> proj)
    float* feats= U + 4*NG;                       // [proj -> decoder)
    float* fnorm= U + 5*NG;                       // [proj -> ip)
    float* ip   = U + 6*NG;                       // [ip -> saliency)

    float* outf  = (float*)d_out;
    float* outso = outf + (size_t)NFINE * FINALD;
    float* outss = outso + NFINE;

    // encoder
    kpconv_fine<<<NFINE/4, 256, 0, stream>>>(points_f, features, neighbors_f, kp_f, W_kp1, x_f);
    hh_kernel<<<NCRS, 256, 0, stream>>>(points_c, points_f, x_f, pool_idx, kp_c, hhg);
    linear_rows<KP*C1D, C2D, 4, false><<<NCRS/4, C2D, 0, stream>>>(hhg, W_kp2, nullptr, x_c);
    linear_rows<C2D, GD, 4, true><<<NCRS/4, GD, 0, stream>>>(x_c, W_bottle, b_bottle, feats_c);

    // GNN
    knn_kernel<<<NCRS, 256, 0, stream>>>(points_c, knn_b);
    self_gemm<<<NCRS/4, 512, 0, stream>>>(feats_c, W_self1, Y1);
    edge_max<<<NCRS, 256, 0, stream>>>(Y1, knn_b, b_self1, g1);
    qkv_kernel<<<NCRS/4, 256, 0, stream>>>(g1, Wq, Wk, Wv, qb, kb, vb);
    attn_flash<<<1024, 256, 0, stream>>>(qb, kb, vb, pm, pl, pacc);
    attn_combine<<<NCRS, 256, 0, stream>>>(pm, pl, pacc, msg);
    cross_combine<<<NCRS/4, 256, 0, stream>>>(g1, msg, W_cross, b_cross, g2);
    self_gemm<<<NCRS/4, 512, 0, stream>>>(g2, W_self2, Y2);
    edge_max<<<NCRS, 256, 0, stream>>>(Y2, knn_b, b_self2, g3);

    // head
    proj_fused<<<NCRS, 256, 0, stream>>>(g3, W_proj, b_proj, W_score, b_score, feats, fnorm, scores);
    ip_kernel<<<NSRC, 256, 0, stream>>>(fnorm, ip);
    saliency_kernel<false><<<NSRC, 256, 0, stream>>>(ip, scores + NSRC, epsilon, sal);
    saliency_kernel<true><<<NSRC, 256, 0, stream>>>(ip, scores, epsilon, sal + NSRC);

    // decoder
    decoder_kernel<<<(NFINE + 255)/256, 256, 0, stream>>>(feats, scores, sal, x_f, upsample_idx,
                                                          W_dec, b_dec, outf, outso, outss);
}